// Round 10
// baseline (526.389 us; speedup 1.0000x reference)
//
#include <hip/hip_runtime.h>
#include <hip/hip_bf16.h>
#include <stdint.h>

typedef __hip_bfloat16 bf16;
using bf16x8 = __attribute__((ext_vector_type(8))) short;   // 8 bf16 (4 VGPRs)
using f32x4  = __attribute__((ext_vector_type(4))) float;   // 4 fp32

// ---------------------------------------------------------------- utilities

__device__ __forceinline__ void gload_lds16(const void* g, void* l) {
  using gchar = __attribute__((address_space(1))) char;
  using lchar = __attribute__((address_space(3))) char;
  gchar* gp = reinterpret_cast<gchar*>(reinterpret_cast<uintptr_t>(g));
  lchar* lp = reinterpret_cast<lchar*>(static_cast<uint32_t>(reinterpret_cast<uintptr_t>(l)));
  __builtin_amdgcn_global_load_lds(gp, lp, 16, 0, 0);
}

__device__ __forceinline__ unsigned short f2bf_bits(float x) {
  uint32_t u = __float_as_uint(x);
  uint32_t r = (u + 0x7fffu + ((u >> 16) & 1u)) >> 16;
  return (unsigned short)r;
}

// ------------------------------------------------ weight transpose fp32->bf16
template <int PERM>
__global__ __launch_bounds__(256) void transpose_bf16(
    const float* __restrict__ W, bf16* __restrict__ Wt, int K, int N) {
  __shared__ float t[32][33];
  const int n0 = blockIdx.x * 32, k0 = blockIdx.y * 32;
  const int tx = threadIdx.x & 31, ty = threadIdx.x >> 5;
  #pragma unroll
  for (int i = ty; i < 32; i += 8) t[i][tx] = W[(size_t)(k0 + i) * N + n0 + tx];
  __syncthreads();
  #pragma unroll
  for (int i = ty; i < 32; i += 8) {
    int n = n0 + i;
    int np;
    if constexpr (PERM == 0) np = n;
    else if constexpr (PERM == 1) np = (n & 15) * 64 + (n >> 4);
    else { int base = n & 1024, m = n & 1023; np = base + (m & 15) * 64 + (m >> 4); }
    Wt[(size_t)np * K + k0 + tx] = __float2bfloat16(t[tx][i]);
  }
}

// ------------------------------------------------ y -> bf16 (padded to 2560 rows)
__global__ __launch_bounds__(256) void conv_y(
    const float* __restrict__ y, bf16* __restrict__ yb) {
  int i = blockIdx.x * 256 + threadIdx.x;
  float v = (i < 2464 * 1024) ? y[i] : 0.f;
  yb[i] = __float2bfloat16(v);
}

// ------------------------------------------------ silu(noise) -> bf16, pad to 128 rows
__global__ __launch_bounds__(256) void silu_pad(
    const float* __restrict__ noise, bf16* __restrict__ Apad) {
  int i = blockIdx.x * 256 + threadIdx.x;
  float v = 0.f;
  if (i < 32 * 1024) {
    float x = noise[i];
    v = x / (1.f + __expf(-x));
  }
  Apad[i] = __float2bfloat16(v);
}

// ------------------------------------------------ LN + modulate -> bf16
__global__ __launch_bounds__(256) void ln_mod(
    const float* __restrict__ x, const float* __restrict__ ada,
    int shOff, int scOff, bf16* __restrict__ out) {
  const int row = blockIdx.x, b = row >> 8, tid = threadIdx.x;
  const float* xr = x + (size_t)row * 1024;
  float v[4], s = 0.f, ss = 0.f;
  #pragma unroll
  for (int i = 0; i < 4; ++i) {
    v[i] = xr[tid + i * 256];
    s += v[i]; ss += v[i] * v[i];
  }
  #pragma unroll
  for (int o = 32; o; o >>= 1) { s += __shfl_xor(s, o); ss += __shfl_xor(ss, o); }
  __shared__ float red[8];
  const int w = tid >> 6;
  if ((tid & 63) == 0) { red[w] = s; red[w + 4] = ss; }
  __syncthreads();
  s = red[0] + red[1] + red[2] + red[3];
  ss = red[4] + red[5] + red[6] + red[7];
  float mu = s * (1.f / 1024.f);
  float var = ss * (1.f / 1024.f) - mu * mu;
  float rstd = rsqrtf(var + 1e-6f);
  const float* adab = ada + (size_t)b * 6144;
  #pragma unroll
  for (int i = 0; i < 4; ++i) {
    int c = tid + i * 256;
    float o = (v[i] - mu) * rstd * (1.f + adab[scOff + c]) + adab[shOff + c];
    out[(size_t)row * 1024 + c] = __float2bfloat16(o);
  }
}

// ------------------------------------------------ generic bf16 MFMA GEMM (128^2)
enum { EPI_STORE = 0, EPI_GELU = 1, EPI_PROJ = 2, EPI_OUT = 3, EPI_ADAF = 4 };

template <int EPI>
__global__ __launch_bounds__(256, 2) void gemm_bf16(
    const bf16* __restrict__ A, const bf16* __restrict__ Bt,
    int N, int K, int gx, int grpG, int xcdP,
    const float* __restrict__ bias, const float* __restrict__ ada, int adaOff,
    const float* __restrict__ resid, float* __restrict__ outF,
    bf16* __restrict__ outB) {
  __shared__ bf16 As[128 * 64];
  __shared__ bf16 Bs[128 * 64];
  const int tid = threadIdx.x;
  const int w = tid >> 6, lane = tid & 63;
  const int wr = w >> 1, wc = w & 1;
  const int lr = lane >> 4, lc = lane & 15;

  const int flat = blockIdx.x;
  const int xcd = flat & 7, j = flat >> 3;
  const int cpg = gx / grpG;
  const int grp = xcd / xcdP, par = xcd % xcdP;
  const int bx = grp * cpg + j % cpg;
  const int by = (j / cpg) * xcdP + par;
  const int mBase = by * 128, nBase = bx * 128;

  f32x4 acc[4][4];
  #pragma unroll
  for (int mi = 0; mi < 4; ++mi)
    #pragma unroll
    for (int ni = 0; ni < 4; ++ni)
      #pragma unroll
      for (int j2 = 0; j2 < 4; ++j2) acc[mi][ni][j2] = 0.f;

  const int nK = K >> 6;
  for (int ks = 0; ks < nK; ++ks) {
    const int k0 = ks << 6;
    #pragma unroll
    for (int i = 0; i < 4; ++i) {
      int t16 = w * 256 + i * 64 + lane;
      int row = t16 >> 3;
      int cL = ((t16 & 7) ^ (row & 7)) << 3;
      gload_lds16(A + (size_t)(mBase + row) * K + k0 + cL, (char*)As + t16 * 16);
      gload_lds16(Bt + (size_t)(nBase + row) * K + k0 + cL, (char*)Bs + t16 * 16);
    }
    __syncthreads();
    #pragma unroll
    for (int kk = 0; kk < 2; ++kk) {
      bf16x8 af[4], bfr[4];
      #pragma unroll
      for (int mi = 0; mi < 4; ++mi) {
        int row = wr * 64 + mi * 16 + lc;
        int byte = row * 128 + ((kk * 64 + lr * 16) ^ ((row & 7) << 4));
        af[mi] = *reinterpret_cast<const bf16x8*>((const char*)As + byte);
      }
      #pragma unroll
      for (int ni = 0; ni < 4; ++ni) {
        int row = wc * 64 + ni * 16 + lc;
        int byte = row * 128 + ((kk * 64 + lr * 16) ^ ((row & 7) << 4));
        bfr[ni] = *reinterpret_cast<const bf16x8*>((const char*)Bs + byte);
      }
      #pragma unroll
      for (int mi = 0; mi < 4; ++mi)
        #pragma unroll
        for (int ni = 0; ni < 4; ++ni)
          acc[mi][ni] = __builtin_amdgcn_mfma_f32_16x16x32_bf16(
              af[mi], bfr[ni], acc[mi][ni], 0, 0, 0);
    }
    __syncthreads();
  }

  const int rB = mBase + wr * 64, cB = nBase + wc * 64;
  #pragma unroll
  for (int mi = 0; mi < 4; ++mi) {
    #pragma unroll
    for (int ni = 0; ni < 4; ++ni) {
      #pragma unroll
      for (int j2 = 0; j2 < 4; ++j2) {
        int r = rB + mi * 16 + lr * 4 + j2;
        int c = cB + ni * 16 + lc;
        float v = acc[mi][ni][j2];
        if (bias) v += bias[c];
        if constexpr (EPI == EPI_STORE) {
          outB[(size_t)r * N + c] = __float2bfloat16(v);
        } else if constexpr (EPI == EPI_GELU) {
          float e = __expf(1.5957691216057308f * v + 0.07135481627260086f * v * v * v);
          float t = 1.f - 2.f / (e + 1.f);
          outB[(size_t)r * N + c] = __float2bfloat16(0.5f * v * (1.f + t));
        } else if constexpr (EPI == EPI_PROJ) {
          int b = r >> 8;
          float g = ada[(size_t)b * 6144 + adaOff + c];
          float o = resid[(size_t)r * 1024 + c] + g * v;
          outF[(size_t)r * 1024 + c] = o;
          outB[(size_t)r * 1024 + c] = __float2bfloat16(o);
        } else if constexpr (EPI == EPI_OUT) {
          int b = r >> 8;
          float g = ada[(size_t)b * 6144 + adaOff + c];
          outF[(size_t)r * 1024 + c] = resid[(size_t)r * 1024 + c] + g * v;
        } else {
          if (r < 32) outF[(size_t)r * N + c] = v;
        }
      }
    }
  }
}

// ------------------------------------------------ 256^2 quadrant 8-phase GEMM
// (verified r9) 512 thr = 8 waves (2M x 4N), per-wave C = 128x64. BK=64.
template <int EPI>
__global__ __launch_bounds__(512, 1) void gemm8q(
    const bf16* __restrict__ A, const bf16* __restrict__ Bt,
    int N, int K, int gx, int grpG, int xcdP,
    const float* __restrict__ bias, bf16* __restrict__ outB) {
  __shared__ bf16 AS[2][2][128 * 64];              // 64 KB [par][half]
  __shared__ bf16 BS[2][2][128 * 64];              // 64 KB
  const int tid = threadIdx.x;
  const int w = tid >> 6, lane = tid & 63;
  const int wr = w >> 2, wc = w & 3;
  const int lr = lane >> 4, lc = lane & 15;

  const int flat = blockIdx.x;
  const int xcd = flat & 7, jj = flat >> 3;
  const int cpg = gx / grpG;
  const int grp = xcd / xcdP, par_ = xcd % xcdP;
  const int bx = grp * cpg + jj % cpg;
  const int by = (jj / cpg) * xcdP + par_;
  const int mBase = by * 256, nBase = bx * 256;
  const int nT = K >> 6;

  f32x4 acc[8][4];
  #pragma unroll
  for (int mi = 0; mi < 8; ++mi)
    #pragma unroll
    for (int ni = 0; ni < 4; ++ni) acc[mi][ni] = f32x4{0.f, 0.f, 0.f, 0.f};

  auto STAGE_A = [&](int th, int h) {
    if (th >= nT) return;
    const int k0 = th << 6;
    char* dst = (char*)&AS[th & 1][h][0];
    #pragma unroll
    for (int i = 0; i < 2; ++i) {
      int ck = i * 512 + tid;
      int rr = ck >> 3, c = ck & 7;
      int grow = mBase + (rr & 63) + ((rr >> 6) << 7) + h * 64;
      gload_lds16(A + (size_t)grow * K + k0 + ((c ^ (rr & 7)) << 3), dst + ck * 16);
    }
  };
  auto STAGE_B = [&](int th, int h) {
    if (th >= nT) return;
    const int k0 = th << 6;
    char* dst = (char*)&BS[th & 1][h][0];
    #pragma unroll
    for (int i = 0; i < 2; ++i) {
      int ck = i * 512 + tid;
      int rr = ck >> 3, c = ck & 7;
      int grow = nBase + ((rr >> 5) << 6) + h * 32 + (rr & 31);
      gload_lds16(Bt + (size_t)grow * K + k0 + ((c ^ (rr & 7)) << 3), dst + ck * 16);
    }
  };

  STAGE_A(0, 0); STAGE_A(0, 1); STAGE_B(0, 0); STAGE_B(0, 1);
  STAGE_A(1, 0); STAGE_A(1, 1);

  for (int t = 0; t < nT; ++t) {
    if (t == nT - 1) { asm volatile("s_waitcnt vmcnt(0)" ::: "memory"); }
    else             { asm volatile("s_waitcnt vmcnt(4)" ::: "memory"); }
    __builtin_amdgcn_s_barrier();

    const int p = t & 1;
    const char* A0 = (const char*)&AS[p][0][0];
    const char* A1 = (const char*)&AS[p][1][0];
    const char* B0 = (const char*)&BS[p][0][0];
    const char* B1 = (const char*)&BS[p][1][0];

    bf16x8 af0[2][4], af1[2][4], bf01[2][2], bf23[2][2];

    // ---- P0
    #pragma unroll
    for (int kk = 0; kk < 2; ++kk) {
      #pragma unroll
      for (int mi = 0; mi < 4; ++mi) {
        int rr = wr * 64 + mi * 16 + lc;
        af0[kk][mi] = *reinterpret_cast<const bf16x8*>(
            A0 + rr * 128 + ((kk * 64 + lr * 16) ^ ((rr & 7) << 4)));
      }
      #pragma unroll
      for (int ni = 0; ni < 2; ++ni) {
        int rr = wc * 32 + ni * 16 + lc;
        bf01[kk][ni] = *reinterpret_cast<const bf16x8*>(
            B0 + rr * 128 + ((kk * 64 + lr * 16) ^ ((rr & 7) << 4)));
      }
    }
    STAGE_B(t + 1, 0);
    __builtin_amdgcn_s_barrier();
    asm volatile("s_waitcnt lgkmcnt(0)" ::: "memory");
    __builtin_amdgcn_sched_barrier(0);
    __builtin_amdgcn_s_setprio(1);
    #pragma unroll
    for (int kk = 0; kk < 2; ++kk)
      #pragma unroll
      for (int mi = 0; mi < 4; ++mi)
        #pragma unroll
        for (int ni = 0; ni < 2; ++ni)
          acc[mi][ni] = __builtin_amdgcn_mfma_f32_16x16x32_bf16(
              af0[kk][mi], bf01[kk][ni], acc[mi][ni], 0, 0, 0);
    __builtin_amdgcn_s_setprio(0);
    __builtin_amdgcn_s_barrier();

    // ---- P1
    #pragma unroll
    for (int kk = 0; kk < 2; ++kk)
      #pragma unroll
      for (int ni = 0; ni < 2; ++ni) {
        int rr = wc * 32 + ni * 16 + lc;
        bf23[kk][ni] = *reinterpret_cast<const bf16x8*>(
            B1 + rr * 128 + ((kk * 64 + lr * 16) ^ ((rr & 7) << 4)));
      }
    STAGE_B(t + 1, 1);
    __builtin_amdgcn_s_barrier();
    asm volatile("s_waitcnt lgkmcnt(0)" ::: "memory");
    __builtin_amdgcn_sched_barrier(0);
    __builtin_amdgcn_s_setprio(1);
    #pragma unroll
    for (int kk = 0; kk < 2; ++kk)
      #pragma unroll
      for (int mi = 0; mi < 4; ++mi)
        #pragma unroll
        for (int ni = 0; ni < 2; ++ni)
          acc[mi][ni + 2] = __builtin_amdgcn_mfma_f32_16x16x32_bf16(
              af0[kk][mi], bf23[kk][ni], acc[mi][ni + 2], 0, 0, 0);
    __builtin_amdgcn_s_setprio(0);
    __builtin_amdgcn_s_barrier();

    // ---- P2
    #pragma unroll
    for (int kk = 0; kk < 2; ++kk)
      #pragma unroll
      for (int mi = 0; mi < 4; ++mi) {
        int rr = wr * 64 + mi * 16 + lc;
        af1[kk][mi] = *reinterpret_cast<const bf16x8*>(
            A1 + rr * 128 + ((kk * 64 + lr * 16) ^ ((rr & 7) << 4)));
      }
    STAGE_A(t + 2, 0);
    __builtin_amdgcn_s_barrier();
    asm volatile("s_waitcnt lgkmcnt(0)" ::: "memory");
    __builtin_amdgcn_sched_barrier(0);
    __builtin_amdgcn_s_setprio(1);
    #pragma unroll
    for (int kk = 0; kk < 2; ++kk)
      #pragma unroll
      for (int mi = 0; mi < 4; ++mi)
        #pragma unroll
        for (int ni = 0; ni < 2; ++ni)
          acc[mi + 4][ni] = __builtin_amdgcn_mfma_f32_16x16x32_bf16(
              af1[kk][mi], bf01[kk][ni], acc[mi + 4][ni], 0, 0, 0);
    __builtin_amdgcn_s_setprio(0);
    __builtin_amdgcn_s_barrier();

    // ---- P3
    STAGE_A(t + 2, 1);
    __builtin_amdgcn_s_barrier();
    __builtin_amdgcn_s_setprio(1);
    #pragma unroll
    for (int kk = 0; kk < 2; ++kk)
      #pragma unroll
      for (int mi = 0; mi < 4; ++mi)
        #pragma unroll
        for (int ni = 0; ni < 2; ++ni)
          acc[mi + 4][ni + 2] = __builtin_amdgcn_mfma_f32_16x16x32_bf16(
              af1[kk][mi], bf23[kk][ni], acc[mi + 4][ni + 2], 0, 0, 0);
    __builtin_amdgcn_s_setprio(0);
    __builtin_amdgcn_s_barrier();
  }

  const int rB = mBase + wr * 128, cB = nBase + wc * 64;
  #pragma unroll
  for (int mi = 0; mi < 8; ++mi) {
    #pragma unroll
    for (int ni = 0; ni < 4; ++ni) {
      #pragma unroll
      for (int j2 = 0; j2 < 4; ++j2) {
        int r = rB + mi * 16 + lr * 4 + j2;
        int c = cB + ni * 16 + lc;
        float v = acc[mi][ni][j2] + bias[c];
        if constexpr (EPI == EPI_STORE) {
          outB[(size_t)r * N + c] = __float2bfloat16(v);
        } else {  // EPI_GELU
          float e = __expf(1.5957691216057308f * v + 0.07135481627260086f * v * v * v);
          float t2 = 1.f - 2.f / (e + 1.f);
          outB[(size_t)r * N + c] = __float2bfloat16(0.5f * v * (1.f + t2));
        }
      }
    }
  }
}

// ------------------------------------------------ 256x128 quadrant 8-phase GEMM
// Same verified skeleton as gemm8q, BN=128: per-wave C = 128x32 (acc[8][2]).
// Phases = (mi-half x kk), 8 MFMA each; reads 12/0/8/0. Stage: P0 B(t+1,0),
// P1 A(t+2,0) [A0 readers drained at P0-end barrier], P2 B(t+1,1),
// P3 A(t+2,1) [A1 readers drained at P2-end]. B -> opposite parity buffer
// (always safe). Boundary vmcnt(2) = A(t+1,1)'s 2 loads; t=0: 4; last: 0.
// LDS 96 KB. Requires M%256==0, N%128==0, K%64==0, K>=128.
template <int EPI>
__global__ __launch_bounds__(512, 1) void gemm8q2(
    const bf16* __restrict__ A, const bf16* __restrict__ Bt,
    int N, int K, int gx, int grpG, int xcdP,
    const float* __restrict__ bias, const float* __restrict__ ada, int adaOff,
    const float* __restrict__ resid, float* __restrict__ outF,
    bf16* __restrict__ outB) {
  __shared__ bf16 AS[2][2][128 * 64];              // 64 KB
  __shared__ bf16 BS[2][2][64 * 64];               // 32 KB
  const int tid = threadIdx.x;
  const int w = tid >> 6, lane = tid & 63;
  const int wr = w >> 2, wc = w & 3;
  const int lr = lane >> 4, lc = lane & 15;

  const int flat = blockIdx.x;
  const int xcd = flat & 7, jj = flat >> 3;
  const int cpg = gx / grpG;
  const int grp = xcd / xcdP, par_ = xcd % xcdP;
  const int bx = grp * cpg + jj % cpg;
  const int by = (jj / cpg) * xcdP + par_;
  const int mBase = by * 256, nBase = bx * 128;
  const int nT = K >> 6;

  f32x4 acc[8][2];
  #pragma unroll
  for (int mi = 0; mi < 8; ++mi)
    #pragma unroll
    for (int ni = 0; ni < 2; ++ni) acc[mi][ni] = f32x4{0.f, 0.f, 0.f, 0.f};

  // A-half h rows (interleaved): {h*64..+63} u {128+h*64..+63}
  auto STAGE_A = [&](int th, int h) {
    if (th >= nT) return;
    const int k0 = th << 6;
    char* dst = (char*)&AS[th & 1][h][0];
    #pragma unroll
    for (int i = 0; i < 2; ++i) {
      int ck = i * 512 + tid;
      int rr = ck >> 3, c = ck & 7;
      int grow = mBase + (rr & 63) + ((rr >> 6) << 7) + h * 64;
      gload_lds16(A + (size_t)grow * K + k0 + ((c ^ (rr & 7)) << 3), dst + ck * 16);
    }
  };
  // B-half h = rows h*64..h*64+63 of the 128-row B tile (1 load/thread)
  auto STAGE_B = [&](int th, int h) {
    if (th >= nT) return;
    const int k0 = th << 6;
    char* dst = (char*)&BS[th & 1][h][0];
    int ck = tid;
    int rr = ck >> 3, c = ck & 7;
    int grow = nBase + h * 64 + rr;
    gload_lds16(Bt + (size_t)grow * K + k0 + ((c ^ (rr & 7)) << 3), dst + ck * 16);
  };

  // prologue: tile0 complete + tile1 A-halves (10 loads/thread)
  STAGE_A(0, 0); STAGE_A(0, 1); STAGE_B(0, 0); STAGE_B(0, 1);
  STAGE_A(1, 0); STAGE_A(1, 1);

  for (int t = 0; t < nT; ++t) {
    if (t == nT - 1)      { asm volatile("s_waitcnt vmcnt(0)" ::: "memory"); }
    else if (t == 0)      { asm volatile("s_waitcnt vmcnt(4)" ::: "memory"); }
    else                  { asm volatile("s_waitcnt vmcnt(2)" ::: "memory"); }
    __builtin_amdgcn_s_barrier();

    const int p = t & 1;
    const char* A0 = (const char*)&AS[p][0][0];
    const char* A1 = (const char*)&AS[p][1][0];
    const char* Bh = (const char*)&BS[p][wc >> 1][0];
    const int rbB = (wc & 1) * 32 + lc;            // + ni*16

    bf16x8 af0[2][4], af1[2][4], bfv[2][2];

    // ---- P0: read af0(8) + bfv(4); stage B(t+1,0); MFMA mi0-3 x kk0
    #pragma unroll
    for (int kk = 0; kk < 2; ++kk) {
      #pragma unroll
      for (int mi = 0; mi < 4; ++mi) {
        int rr = wr * 64 + mi * 16 + lc;
        af0[kk][mi] = *reinterpret_cast<const bf16x8*>(
            A0 + rr * 128 + ((kk * 64 + lr * 16) ^ ((rr & 7) << 4)));
      }
      #pragma unroll
      for (int ni = 0; ni < 2; ++ni) {
        int rr = rbB + ni * 16;
        bfv[kk][ni] = *reinterpret_cast<const bf16x8*>(
            Bh + rr * 128 + ((kk * 64 + lr * 16) ^ ((rr & 7) << 4)));
      }
    }
    STAGE_B(t + 1, 0);
    __builtin_amdgcn_s_barrier();
    asm volatile("s_waitcnt lgkmcnt(0)" ::: "memory");
    __builtin_amdgcn_sched_barrier(0);
    __builtin_amdgcn_s_setprio(1);
    #pragma unroll
    for (int mi = 0; mi < 4; ++mi)
      #pragma unroll
      for (int ni = 0; ni < 2; ++ni)
        acc[mi][ni] = __builtin_amdgcn_mfma_f32_16x16x32_bf16(
            af0[0][mi], bfv[0][ni], acc[mi][ni], 0, 0, 0);
    __builtin_amdgcn_s_setprio(0);
    __builtin_amdgcn_s_barrier();

    // ---- P1: stage A(t+2,0); MFMA mi0-3 x kk1 (register-only)
    STAGE_A(t + 2, 0);
    __builtin_amdgcn_s_barrier();
    __builtin_amdgcn_s_setprio(1);
    #pragma unroll
    for (int mi = 0; mi < 4; ++mi)
      #pragma unroll
      for (int ni = 0; ni < 2; ++ni)
        acc[mi][ni] = __builtin_amdgcn_mfma_f32_16x16x32_bf16(
            af0[1][mi], bfv[1][ni], acc[mi][ni], 0, 0, 0);
    __builtin_amdgcn_s_setprio(0);
    __builtin_amdgcn_s_barrier();

    // ---- P2: read af1(8); stage B(t+1,1); MFMA mi4-7 x kk0
    #pragma unroll
    for (int kk = 0; kk < 2; ++kk)
      #pragma unroll
      for (int mi = 0; mi < 4; ++mi) {
        int rr = wr * 64 + mi * 16 + lc;
        af1[kk][mi] = *reinterpret_cast<const bf16x8*>(
            A1 + rr * 128 + ((kk * 64 + lr * 16) ^ ((rr & 7) << 4)));
      }
    STAGE_B(t + 1, 1);
    __builtin_amdgcn_s_barrier();
    asm volatile("s_waitcnt lgkmcnt(0)" ::: "memory");
    __builtin_amdgcn_sched_barrier(0);
    __builtin_amdgcn_s_setprio(1);
    #pragma unroll
    for (int mi = 0; mi < 4; ++mi)
      #pragma unroll
      for (int ni = 0; ni < 2; ++ni)
        acc[mi + 4][ni] = __builtin_amdgcn_mfma_f32_16x16x32_bf16(
            af1[0][mi], bfv[0][ni], acc[mi + 4][ni], 0, 0, 0);
    __builtin_amdgcn_s_setprio(0);
    __builtin_amdgcn_s_barrier();

    // ---- P3: stage A(t+2,1); MFMA mi4-7 x kk1 (register-only)
    STAGE_A(t + 2, 1);
    __builtin_amdgcn_s_barrier();
    __builtin_amdgcn_s_setprio(1);
    #pragma unroll
    for (int mi = 0; mi < 4; ++mi)
      #pragma unroll
      for (int ni = 0; ni < 2; ++ni)
        acc[mi + 4][ni] = __builtin_amdgcn_mfma_f32_16x16x32_bf16(
            af1[1][mi], bfv[1][ni], acc[mi + 4][ni], 0, 0, 0);
    __builtin_amdgcn_s_setprio(0);
    __builtin_amdgcn_s_barrier();
  }

  const int rB = mBase + wr * 128, cB = nBase + wc * 32;
  #pragma unroll
  for (int mi = 0; mi < 8; ++mi) {
    #pragma unroll
    for (int ni = 0; ni < 2; ++ni) {
      #pragma unroll
      for (int j2 = 0; j2 < 4; ++j2) {
        int r = rB + mi * 16 + lr * 4 + j2;
        int c = cB + ni * 16 + lc;
        float v = acc[mi][ni][j2];
        if (bias) v += bias[c];
        if constexpr (EPI == EPI_STORE) {
          outB[(size_t)r * N + c] = __float2bfloat16(v);
        } else if constexpr (EPI == EPI_GELU) {
          float e = __expf(1.5957691216057308f * v + 0.07135481627260086f * v * v * v);
          float t2 = 1.f - 2.f / (e + 1.f);
          outB[(size_t)r * N + c] = __float2bfloat16(0.5f * v * (1.f + t2));
        } else if constexpr (EPI == EPI_PROJ) {
          int b = r >> 8;
          float g = ada[(size_t)b * 6144 + adaOff + c];
          float o = resid[(size_t)r * 1024 + c] + g * v;
          outF[(size_t)r * 1024 + c] = o;
          outB[(size_t)r * 1024 + c] = __float2bfloat16(o);
        } else if constexpr (EPI == EPI_OUT) {
          int b = r >> 8;
          float g = ada[(size_t)b * 6144 + adaOff + c];
          outF[(size_t)r * 1024 + c] = resid[(size_t)r * 1024 + c] + g * v;
        }
      }
    }
  }
}

// ------------------------------------------------ window attention (attn1, MFMA)
__global__ __launch_bounds__(512, 1) void attn1_mfma(
    const bf16* __restrict__ qkv, const float* __restrict__ rel,
    bf16* __restrict__ o) {
  __shared__ bf16 Ks[256 * 64];
  __shared__ bf16 Vt[64 * 256];
  __shared__ ushort Pl[8][32 * 40];
  __shared__ float bias_s[964];

  const int tid = threadIdx.x;
  const int w = tid >> 6, lane = tid & 63;
  const int p4 = lane >> 4, c = lane & 15;
  const int bh = blockIdx.x, b = bh >> 4, h = bh & 15;
  const bf16* basep = qkv + (size_t)b * 256 * 3072 + h * 64;

  #pragma unroll
  for (int it = 0; it < 4; ++it) {
    int t16 = it * 512 + tid;
    int row = t16 >> 3;
    int sc = ((t16 & 7) ^ (row & 7)) << 3;
    gload_lds16(basep + (size_t)row * 3072 + 1024 + sc, (char*)Ks + t16 * 16);
  }
  #pragma unroll
  for (int it = 0; it < 4; ++it) {
    int i = it * 512 + tid;
    int key = i >> 3, d0 = (i & 7) * 8;
    int4 u = *reinterpret_cast<const int4*>(basep + (size_t)key * 3072 + 2048 + d0);
    const ushort* us = reinterpret_cast<const ushort*>(&u);
    #pragma unroll
    for (int j = 0; j < 8; ++j) {
      int dh = d0 + j;
      int byte = dh * 512 + ((key * 2) ^ ((dh & 7) << 4));
      *reinterpret_cast<ushort*>((char*)Vt + byte) = us[j];
    }
  }
  for (int i = tid; i < 964; i += 512) bias_s[i] = rel[i * 16 + h];

  bf16x8 qf[2][2];
  #pragma unroll
  for (int mi = 0; mi < 2; ++mi)
    #pragma unroll
    for (int s = 0; s < 2; ++s) {
      int q = w * 32 + mi * 16 + c;
      int dh = s * 32 + p4 * 8;
      int4 u = *reinterpret_cast<const int4*>(basep + (size_t)q * 3072 + dh);
      uint32_t a[4] = {(uint32_t)u.x, (uint32_t)u.y, (uint32_t)u.z, (uint32_t)u.w};
      bf16x8 r;
      #pragma unroll
      for (int t = 0; t < 4; ++t) {
        float lo = __uint_as_float(a[t] << 16) * 0.125f;
        float hi = __uint_as_float(a[t] & 0xffff0000u) * 0.125f;
        r[2 * t]     = (short)(__float_as_uint(lo) >> 16);
        r[2 * t + 1] = (short)(__float_as_uint(hi) >> 16);
      }
      qf[mi][s] = r;
    }
  __syncthreads();

  float m_run[2][4], l_run[2][4];
  f32x4 oacc[2][4];
  #pragma unroll
  for (int mi = 0; mi < 2; ++mi)
    #pragma unroll
    for (int j = 0; j < 4; ++j) {
      m_run[mi][j] = -1e30f; l_run[mi][j] = 0.f;
      oacc[mi][j] = f32x4{0.f, 0.f, 0.f, 0.f};
    }

  ushort* Pw = &Pl[w][0];
  const int colterm = p4 * 4 - c + 15;

  for (int kt = 0; kt < 8; ++kt) {
    f32x4 sacc[2][2];
    #pragma unroll
    for (int mi = 0; mi < 2; ++mi)
      #pragma unroll
      for (int nf = 0; nf < 2; ++nf) {
        int bi = ((w * 2 + mi) - (kt * 2 + nf) + 15) * 31 + colterm;
        #pragma unroll
        for (int j = 0; j < 4; ++j) sacc[mi][nf][j] = bias_s[bi + j];
      }
    #pragma unroll
    for (int nf = 0; nf < 2; ++nf) {
      int key = kt * 32 + nf * 16 + c;
      #pragma unroll
      for (int s = 0; s < 2; ++s) {
        int byte = key * 128 + (((s * 4 + p4) ^ (key & 7)) << 4);
        bf16x8 kb = *reinterpret_cast<const bf16x8*>((const char*)Ks + byte);
        #pragma unroll
        for (int mi = 0; mi < 2; ++mi)
          sacc[mi][nf] = __builtin_amdgcn_mfma_f32_16x16x32_bf16(
              qf[mi][s], kb, sacc[mi][nf], 0, 0, 0);
      }
    }
    float sf[2][4];
    #pragma unroll
    for (int mi = 0; mi < 2; ++mi)
      #pragma unroll
      for (int j = 0; j < 4; ++j) {
        float cm = fmaxf(sacc[mi][0][j], sacc[mi][1][j]);
        cm = fmaxf(cm, __shfl_xor(cm, 1));
        cm = fmaxf(cm, __shfl_xor(cm, 2));
        cm = fmaxf(cm, __shfl_xor(cm, 4));
        cm = fmaxf(cm, __shfl_xor(cm, 8));
        float nm = fmaxf(m_run[mi][j], cm);
        sf[mi][j] = __expf(m_run[mi][j] - nm);
        m_run[mi][j] = nm;
        l_run[mi][j] *= sf[mi][j];
      }
    #pragma unroll
    for (int mi = 0; mi < 2; ++mi)
      #pragma unroll
      for (int nf = 0; nf < 4; ++nf)
        #pragma unroll
        for (int j = 0; j < 4; ++j) oacc[mi][nf][j] *= sf[mi][j];
    #pragma unroll
    for (int mi = 0; mi < 2; ++mi) {
      #pragma unroll
      for (int nf = 0; nf < 2; ++nf)
        #pragma unroll
        for (int j = 0; j < 4; ++j)
          sacc[mi][nf][j] = __expf(sacc[mi][nf][j] - m_run[mi][j]);
      #pragma unroll
      for (int j = 0; j < 4; ++j) {
        float lp = sacc[mi][0][j] + sacc[mi][1][j];
        lp += __shfl_xor(lp, 1);
        lp += __shfl_xor(lp, 2);
        lp += __shfl_xor(lp, 4);
        lp += __shfl_xor(lp, 8);
        l_run[mi][j] += lp;
      }
      #pragma unroll
      for (int nf = 0; nf < 2; ++nf)
        #pragma unroll
        for (int j = 0; j < 4; ++j)
          Pw[(mi * 16 + p4 * 4 + j) * 40 + nf * 16 + c] =
              f2bf_bits(sacc[mi][nf][j]);
    }
    bf16x8 pa[2], vb[4];
    #pragma unroll
    for (int mi = 0; mi < 2; ++mi)
      pa[mi] = *reinterpret_cast<const bf16x8*>(
          (const char*)Pw + (mi * 16 + c) * 80 + p4 * 16);
    #pragma unroll
    for (int nf = 0; nf < 4; ++nf) {
      int dh = nf * 16 + c;
      int byte = dh * 512 + (((kt * 4 + p4) ^ (dh & 7)) << 4);
      vb[nf] = *reinterpret_cast<const bf16x8*>((const char*)Vt + byte);
    }
    #pragma unroll
    for (int mi = 0; mi < 2; ++mi)
      #pragma unroll
      for (int nf = 0; nf < 4; ++nf)
        oacc[mi][nf] = __builtin_amdgcn_mfma_f32_16x16x32_bf16(
            pa[mi], vb[nf], oacc[mi][nf], 0, 0, 0);
  }

  #pragma unroll
  for (int mi = 0; mi < 2; ++mi) {
    float inv[4];
    #pragma unroll
    for (int j = 0; j < 4; ++j) inv[j] = 1.f / l_run[mi][j];
    #pragma unroll
    for (int nf = 0; nf < 4; ++nf)
      #pragma unroll
      for (int j = 0; j < 4; ++j) {
        int q = w * 32 + mi * 16 + p4 * 4 + j;
        int dh = nf * 16 + c;
        o[((size_t)b * 256 + q) * 1024 + h * 64 + dh] =
            __float2bfloat16(oacc[mi][nf][j] * inv[j]);
      }
  }
}

// ------------------------------------------------ cross attention (attn2, MFMA)
__global__ __launch_bounds__(512, 1) void attn2_mfma(
    const bf16* __restrict__ q2, const bf16* __restrict__ kv,
    bf16* __restrict__ o2) {
  __shared__ bf16 Ks[80 * 64];
  __shared__ bf16 Vt[64 * 128];
  __shared__ ushort Pl[8][32 * 104];

  const int tid = threadIdx.x;
  const int w = tid >> 6, lane = tid & 63;
  const int p4 = lane >> 4, c = lane & 15;
  const int bh = blockIdx.x, b = bh >> 4, h = bh & 15;
  const size_t kvrow0 = (size_t)b * 77;

  {
    int t16 = tid;
    int key = t16 >> 3;
    int sc = ((t16 & 7) ^ (key & 7)) << 3;
    gload_lds16(kv + (kvrow0 + key) * 2048 + h * 64 + sc, (char*)Ks + t16 * 16);
    if (tid < 128) {
      int u16 = 512 + tid; key = u16 >> 3;
      sc = ((u16 & 7) ^ (key & 7)) << 3;
      gload_lds16(kv + (kvrow0 + key) * 2048 + h * 64 + sc, (char*)Ks + u16 * 16);
    }
  }
  for (int i = tid; i < 80 * 8; i += 512) {
    int key = i >> 3, d0 = (i & 7) * 8;
    int4 u = *reinterpret_cast<const int4*>(
        kv + (kvrow0 + key) * 2048 + 1024 + h * 64 + d0);
    const ushort* us = reinterpret_cast<const ushort*>(&u);
    #pragma unroll
    for (int j = 0; j < 8; ++j) {
      int dh = d0 + j;
      int byte = dh * 256 + ((key * 2) ^ ((dh & 7) << 4));
      *reinterpret_cast<ushort*>((char*)Vt + byte) = us[j];
    }
  }
  {
    int row = lane >> 1, colb = 160 + (lane & 1) * 16;
    *reinterpret_cast<int4*>((char*)&Pl[w][0] + row * 208 + colb) =
        int4{0, 0, 0, 0};
  }
  bf16x8 qf[2][2];
  #pragma unroll
  for (int mi = 0; mi < 2; ++mi)
    #pragma unroll
    for (int s = 0; s < 2; ++s) {
      int q = w * 32 + mi * 16 + c;
      int dh = s * 32 + p4 * 8;
      int4 u = *reinterpret_cast<const int4*>(
          q2 + ((size_t)b * 256 + q) * 1024 + h * 64 + dh);
      uint32_t a[4] = {(uint32_t)u.x, (uint32_t)u.y, (uint32_t)u.z, (uint32_t)u.w};
      bf16x8 r;
      #pragma unroll
      for (int t = 0; t < 4; ++t) {
        float lo = __uint_as_float(a[t] << 16) * 0.125f;
        float hi = __uint_as_float(a[t] & 0xffff0000u) * 0.125f;
        r[2 * t]     = (short)(__float_as_uint(lo) >> 16);
        r[2 * t + 1] = (short)(__float_as_uint(hi) >> 16);
      }
      qf[mi][s] = r;
    }
  __syncthreads();

  f32x4 sacc[2][5];
  #pragma unroll
  for (int mi = 0; mi < 2; ++mi)
    #pragma unroll
    for (int nf = 0; nf < 5; ++nf)
      sacc[mi][nf] = f32x4{0.f, 0.f, 0.f, 0.f};
  #pragma unroll
  for (int nf = 0; nf < 5; ++nf) {
    int key = nf * 16 + c;
    #pragma unroll
    for (int s = 0; s < 2; ++s) {
      int byte = key * 128 + (((s * 4 + p4) ^ (key & 7)) << 4);
      bf16x8 kb = *reinterpret_cast<const bf16x8*>((const char*)Ks + byte);
      #pragma unroll
      for (int mi = 0; mi < 2; ++mi)
        sacc[mi][nf] = __builtin_amdgcn_mfma_f32_16x16x32_bf16(
            qf[mi][s], kb, sacc[mi][nf], 0, 0, 0);
    }
  }
  if (c >= 13) {
    #pragma unroll
    for (int mi = 0; mi < 2; ++mi)
      #pragma unroll
      for (int j = 0; j < 4; ++j) sacc[mi][4][j] = -1e30f;
  }
  float lrow[2][4];
  #pragma unroll
  for (int mi = 0; mi < 2; ++mi)
    #pragma unroll
    for (int j = 0; j < 4; ++j) {
      float cm = sacc[mi][0][j];
      #pragma unroll
      for (int nf = 1; nf < 5; ++nf) cm = fmaxf(cm, sacc[mi][nf][j]);
      cm = fmaxf(cm, __shfl_xor(cm, 1));
      cm = fmaxf(cm, __shfl_xor(cm, 2));
      cm = fmaxf(cm, __shfl_xor(cm, 4));
      cm = fmaxf(cm, __shfl_xor(cm, 8));
      float lp = 0.f;
      #pragma unroll
      for (int nf = 0; nf < 5; ++nf) {
        sacc[mi][nf][j] = __expf(sacc[mi][nf][j] - cm);
        lp += sacc[mi][nf][j];
      }
      lp += __shfl_xor(lp, 1);
      lp += __shfl_xor(lp, 2);
      lp += __shfl_xor(lp, 4);
      lp += __shfl_xor(lp, 8);
      lrow[mi][j] = lp;
    }
  ushort* Pw = &Pl[w][0];
  #pragma unroll
  for (int mi = 0; mi < 2; ++mi)
    #pragma unroll
    for (int nf = 0; nf < 5; ++nf)
      #pragma unroll
      for (int j = 0; j < 4; ++j)
        Pw[(mi * 16 + p4 * 4 + j) * 104 + nf * 16 + c] =
            f2bf_bits(sacc[mi][nf][j]);
  f32x4 oacc[2][4];
  #pragma unroll
  for (int mi = 0; mi < 2; ++mi)
    #pragma unroll
    for (int nf = 0; nf < 4; ++nf) oacc[mi][nf] = f32x4{0.f, 0.f, 0.f, 0.f};
  #pragma unroll
  for (int kk = 0; kk < 3; ++kk) {
    bf16x8 pa[2], vb[4];
    #pragma unroll
    for (int mi = 0; mi < 2; ++mi)
      pa[mi] = *reinterpret_cast<const bf16x8*>(
          (const char*)Pw + (mi * 16 + c) * 208 + kk * 64 + p4 * 16);
    #pragma unroll
    for (int nf = 0; nf < 4; ++nf) {
      int dh = nf * 16 + c;
      int byte = dh * 256 + (((kk * 4 + p4) ^ (dh & 7)) << 4);
      vb[nf] = *reinterpret_cast<const bf16x8*>((const char*)Vt + byte);
    }
    #pragma unroll
    for (int mi = 0; mi < 2; ++mi)
      #pragma unroll
      for (int nf = 0; nf < 4; ++nf)
        oacc[mi][nf] = __builtin_amdgcn_mfma_f32_16x16x32_bf16(
            pa[mi], vb[nf], oacc[mi][nf], 0, 0, 0);
  }
  #pragma unroll
  for (int mi = 0; mi < 2; ++mi) {
    float inv[4];
    #pragma unroll
    for (int j = 0; j < 4; ++j) inv[j] = 1.f / lrow[mi][j];
    #pragma unroll
    for (int nf = 0; nf < 4; ++nf)
      #pragma unroll
      for (int j = 0; j < 4; ++j) {
        int q = w * 32 + mi * 16 + p4 * 4 + j;
        int dh = nf * 16 + c;
        o2[((size_t)b * 256 + q) * 1024 + h * 64 + dh] =
            __float2bfloat16(oacc[mi][nf][j] * inv[j]);
      }
  }
}

// ------------------------------------------------ o2 head-major -> xcur += (d*16+h)
__global__ __launch_bounds__(256) void permute_add(
    const bf16* __restrict__ o2, float* __restrict__ xcur) {
  __shared__ float s_lds[1088];
  const int tid = threadIdx.x;
  const int row0 = blockIdx.x * 4;
  for (int r = 0; r < 4; ++r) {
    const int row = row0 + r;
    #pragma unroll
    for (int i = 0; i < 4; ++i) {
      int cc = i * 256 + tid;
      float v = __bfloat162float(o2[(size_t)row * 1024 + cc]);
      s_lds[cc + (cc >> 4)] = v;
    }
    __syncthreads();
    float4 add;
    #pragma unroll
    for (int t = 0; t < 4; ++t) {
      int ct = tid * 4 + t;
      int src = (ct & 15) * 64 + (ct >> 4);
      (&add.x)[t] = s_lds[src + (src >> 4)];
    }
    float4* xp = reinterpret_cast<float4*>(xcur + (size_t)row * 1024 + tid * 4);
    float4 cur = *xp;
    cur.x += add.x; cur.y += add.y; cur.z += add.z; cur.w += add.w;
    *xp = cur;
    __syncthreads();
  }
}

// ---------------------------------------------------------------- launcher

extern "C" void kernel_launch(void* const* d_in, const int* in_sizes, int n_in,
                              void* d_out, int out_size, void* d_ws, size_t ws_size,
                              hipStream_t stream) {
  (void)in_sizes; (void)n_in; (void)out_size; (void)ws_size;
  const float* x      = (const float*)d_in[0];
  const float* noise  = (const float*)d_in[1];
  const float* y      = (const float*)d_in[2];
  const float* W_qkv  = (const float*)d_in[3];
  const float* b_qkv  = (const float*)d_in[4];
  const float* W_proj = (const float*)d_in[5];
  const float* b_proj = (const float*)d_in[6];
  const float* rel    = (const float*)d_in[7];
  const float* W_ada  = (const float*)d_in[8];
  const float* b_ada  = (const float*)d_in[9];
  const float* W_fc1  = (const float*)d_in[10];
  const float* b_fc1  = (const float*)d_in[11];
  const float* W_fc2  = (const float*)d_in[12];
  const float* b_fc2  = (const float*)d_in[13];
  const float* W_q    = (const float*)d_in[14];
  const float* W_kv   = (const float*)d_in[15];

  char* ws = (char*)d_ws;
  size_t off = 0;
  auto alloc = [&](size_t bytes) {
    char* p = ws + off;
    off = (off + bytes + 255) & ~(size_t)255;
    return p;
  };
  float* ada   = (float*)alloc(32u * 6144 * 4);
  float* xcur  = (float*)alloc(8192u * 1024 * 4);
  bf16* WqkvT  = (bf16*)alloc(3072u * 1024 * 2);
  bf16* WprojT = (bf16*)alloc(1024u * 1024 * 2);
  bf16* WqT    = (bf16*)alloc(1024u * 1024 * 2);
  bf16* WkvT   = (bf16*)alloc(2048u * 1024 * 2);
  bf16* Wfc1T  = (bf16*)alloc(4096u * 1024 * 2);
  bf16* Wfc2T  = (bf16*)alloc(1024u * 4096 * 2);
  bf16* WadaT  = (bf16*)alloc(6144u * 1024 * 2);
  bf16* Apad   = (bf16*)alloc(128u * 1024 * 2);
  bf16* hbuf   = (bf16*)alloc(8192u * 1024 * 2);
  bf16* big    = (bf16*)alloc(8192u * 4096 * 2);
  bf16* obuf   = (bf16*)alloc(8192u * 1024 * 2);
  bf16* kvbuf  = (bf16*)alloc(2560u * 2048 * 2);
  bf16* ybuf   = (bf16*)alloc(2560u * 1024 * 2);
  float* outF  = (float*)d_out;

  // weight prep (W_q / W_kv get head-major column permutation)
  transpose_bf16<0><<<dim3(96, 32), 256, 0, stream>>>(W_qkv, WqkvT, 1024, 3072);
  transpose_bf16<0><<<dim3(32, 32), 256, 0, stream>>>(W_proj, WprojT, 1024, 1024);
  transpose_bf16<1><<<dim3(32, 32), 256, 0, stream>>>(W_q, WqT, 1024, 1024);
  transpose_bf16<2><<<dim3(64, 32), 256, 0, stream>>>(W_kv, WkvT, 1024, 2048);
  transpose_bf16<0><<<dim3(128, 32), 256, 0, stream>>>(W_fc1, Wfc1T, 1024, 4096);
  transpose_bf16<0><<<dim3(32, 128), 256, 0, stream>>>(W_fc2, Wfc2T, 4096, 1024);
  transpose_bf16<0><<<dim3(192, 32), 256, 0, stream>>>(W_ada, WadaT, 1024, 6144);
  conv_y<<<2560 * 1024 / 256, 256, 0, stream>>>(y, ybuf);

  // ada = silu(noise) @ W_ada + b_ada (M=32 padded to 128)
  silu_pad<<<512, 256, 0, stream>>>(noise, Apad);
  gemm_bf16<EPI_ADAF><<<48, 256, 0, stream>>>(
      Apad, WadaT, 6144, 1024, 48, 8, 1, b_ada, nullptr, 0, nullptr, ada, nullptr);

  // MSA branch
  ln_mod<<<8192, 256, 0, stream>>>(x, ada, 0, 1024, hbuf);
  gemm8q<EPI_STORE><<<384, 512, 0, stream>>>(            // qkv: 12x32 tiles 256^2
      hbuf, WqkvT, 3072, 1024, 12, 4, 2, b_qkv, big);
  attn1_mfma<<<512, 512, 0, stream>>>(big, rel, obuf);
  gemm8q2<EPI_PROJ><<<256, 512, 0, stream>>>(            // proj: 8x32 tiles 256x128
      obuf, WprojT, 1024, 1024, 8, 4, 2, b_proj, ada, 2048, x, xcur, hbuf);

  // cross-attention branch (head-major q2/kv)
  gemm8q2<EPI_STORE><<<256, 512, 0, stream>>>(           // q2: 8x32 tiles 256x128
      hbuf, WqT, 1024, 1024, 8, 4, 2, nullptr, nullptr, 0, nullptr, nullptr, obuf);
  gemm_bf16<EPI_STORE><<<320, 256, 0, stream>>>(         // kv: 16x20 tiles 128^2
      ybuf, WkvT, 2048, 1024, 16, 8, 1, nullptr, nullptr, 0, nullptr, nullptr, kvbuf);
  attn2_mfma<<<512, 512, 0, stream>>>(obuf, kvbuf, big);
  permute_add<<<2048, 256, 0, stream>>>(big, xcur);

  // MLP branch
  ln_mod<<<8192, 256, 0, stream>>>(xcur, ada, 3072, 4096, hbuf);
  gemm8q<EPI_GELU><<<512, 512, 0, stream>>>(             // fc1: 16x32 tiles 256^2
      hbuf, Wfc1T, 4096, 1024, 16, 4, 2, b_fc1, big);
  gemm8q2<EPI_OUT><<<256, 512, 0, stream>>>(             // fc2: 8x32 tiles 256x128
      big, Wfc2T, 1024, 4096, 8, 4, 2, b_fc2, ada, 5120, xcur, outF, nullptr);
}

// Round 11
// 517.103 us; speedup vs baseline: 1.0180x; 1.0180x over previous
//
#include <hip/hip_runtime.h>
#include <hip/hip_bf16.h>
#include <stdint.h>

typedef __hip_bfloat16 bf16;
using bf16x8 = __attribute__((ext_vector_type(8))) short;   // 8 bf16 (4 VGPRs)
using f32x4  = __attribute__((ext_vector_type(4))) float;   // 4 fp32

// ---------------------------------------------------------------- utilities

__device__ __forceinline__ void gload_lds16(const void* g, void* l) {
  using gchar = __attribute__((address_space(1))) char;
  using lchar = __attribute__((address_space(3))) char;
  gchar* gp = reinterpret_cast<gchar*>(reinterpret_cast<uintptr_t>(g));
  lchar* lp = reinterpret_cast<lchar*>(static_cast<uint32_t>(reinterpret_cast<uintptr_t>(l)));
  __builtin_amdgcn_global_load_lds(gp, lp, 16, 0, 0);
}

__device__ __forceinline__ unsigned short f2bf_bits(float x) {
  uint32_t u = __float_as_uint(x);
  uint32_t r = (u + 0x7fffu + ((u >> 16) & 1u)) >> 16;
  return (unsigned short)r;
}

// ------------------------------------------------ weight transpose fp32->bf16
template <int PERM>
__global__ __launch_bounds__(256) void transpose_bf16(
    const float* __restrict__ W, bf16* __restrict__ Wt, int K, int N) {
  __shared__ float t[32][33];
  const int n0 = blockIdx.x * 32, k0 = blockIdx.y * 32;
  const int tx = threadIdx.x & 31, ty = threadIdx.x >> 5;
  #pragma unroll
  for (int i = ty; i < 32; i += 8) t[i][tx] = W[(size_t)(k0 + i) * N + n0 + tx];
  __syncthreads();
  #pragma unroll
  for (int i = ty; i < 32; i += 8) {
    int n = n0 + i;
    int np;
    if constexpr (PERM == 0) np = n;
    else if constexpr (PERM == 1) np = (n & 15) * 64 + (n >> 4);
    else { int base = n & 1024, m = n & 1023; np = base + (m & 15) * 64 + (m >> 4); }
    Wt[(size_t)np * K + k0 + tx] = __float2bfloat16(t[tx][i]);
  }
}

// ------------------------------------------------ y -> bf16 (padded to 2560 rows)
__global__ __launch_bounds__(256) void conv_y(
    const float* __restrict__ y, bf16* __restrict__ yb) {
  int i = blockIdx.x * 256 + threadIdx.x;
  float v = (i < 2464 * 1024) ? y[i] : 0.f;
  yb[i] = __float2bfloat16(v);
}

// ------------------------------------------------ silu(noise) -> bf16, pad to 128 rows
__global__ __launch_bounds__(256) void silu_pad(
    const float* __restrict__ noise, bf16* __restrict__ Apad) {
  int i = blockIdx.x * 256 + threadIdx.x;
  float v = 0.f;
  if (i < 32 * 1024) {
    float x = noise[i];
    v = x / (1.f + __expf(-x));
  }
  Apad[i] = __float2bfloat16(v);
}

// ------------------------------------------------ LN + modulate -> bf16
__global__ __launch_bounds__(256) void ln_mod(
    const float* __restrict__ x, const float* __restrict__ ada,
    int shOff, int scOff, bf16* __restrict__ out) {
  const int row = blockIdx.x, b = row >> 8, tid = threadIdx.x;
  const float* xr = x + (size_t)row * 1024;
  float v[4], s = 0.f, ss = 0.f;
  #pragma unroll
  for (int i = 0; i < 4; ++i) {
    v[i] = xr[tid + i * 256];
    s += v[i]; ss += v[i] * v[i];
  }
  #pragma unroll
  for (int o = 32; o; o >>= 1) { s += __shfl_xor(s, o); ss += __shfl_xor(ss, o); }
  __shared__ float red[8];
  const int w = tid >> 6;
  if ((tid & 63) == 0) { red[w] = s; red[w + 4] = ss; }
  __syncthreads();
  s = red[0] + red[1] + red[2] + red[3];
  ss = red[4] + red[5] + red[6] + red[7];
  float mu = s * (1.f / 1024.f);
  float var = ss * (1.f / 1024.f) - mu * mu;
  float rstd = rsqrtf(var + 1e-6f);
  const float* adab = ada + (size_t)b * 6144;
  #pragma unroll
  for (int i = 0; i < 4; ++i) {
    int c = tid + i * 256;
    float o = (v[i] - mu) * rstd * (1.f + adab[scOff + c]) + adab[shOff + c];
    out[(size_t)row * 1024 + c] = __float2bfloat16(o);
  }
}

// ------------------------------------------------ generic bf16 MFMA GEMM (128^2)
enum { EPI_STORE = 0, EPI_GELU = 1, EPI_PROJ = 2, EPI_OUT = 3, EPI_ADAF = 4 };

template <int EPI>
__global__ __launch_bounds__(256, 2) void gemm_bf16(
    const bf16* __restrict__ A, const bf16* __restrict__ Bt,
    int N, int K, int gx, int grpG, int xcdP,
    const float* __restrict__ bias, const float* __restrict__ ada, int adaOff,
    const float* __restrict__ resid, float* __restrict__ outF,
    bf16* __restrict__ outB) {
  __shared__ bf16 As[128 * 64];
  __shared__ bf16 Bs[128 * 64];
  const int tid = threadIdx.x;
  const int w = tid >> 6, lane = tid & 63;
  const int wr = w >> 1, wc = w & 1;
  const int lr = lane >> 4, lc = lane & 15;

  const int flat = blockIdx.x;
  const int xcd = flat & 7, j = flat >> 3;
  const int cpg = gx / grpG;
  const int grp = xcd / xcdP, par = xcd % xcdP;
  const int bx = grp * cpg + j % cpg;
  const int by = (j / cpg) * xcdP + par;
  const int mBase = by * 128, nBase = bx * 128;

  f32x4 acc[4][4];
  #pragma unroll
  for (int mi = 0; mi < 4; ++mi)
    #pragma unroll
    for (int ni = 0; ni < 4; ++ni)
      #pragma unroll
      for (int j2 = 0; j2 < 4; ++j2) acc[mi][ni][j2] = 0.f;

  const int nK = K >> 6;
  for (int ks = 0; ks < nK; ++ks) {
    const int k0 = ks << 6;
    #pragma unroll
    for (int i = 0; i < 4; ++i) {
      int t16 = w * 256 + i * 64 + lane;
      int row = t16 >> 3;
      int cL = ((t16 & 7) ^ (row & 7)) << 3;
      gload_lds16(A + (size_t)(mBase + row) * K + k0 + cL, (char*)As + t16 * 16);
      gload_lds16(Bt + (size_t)(nBase + row) * K + k0 + cL, (char*)Bs + t16 * 16);
    }
    __syncthreads();
    #pragma unroll
    for (int kk = 0; kk < 2; ++kk) {
      bf16x8 af[4], bfr[4];
      #pragma unroll
      for (int mi = 0; mi < 4; ++mi) {
        int row = wr * 64 + mi * 16 + lc;
        int byte = row * 128 + ((kk * 64 + lr * 16) ^ ((row & 7) << 4));
        af[mi] = *reinterpret_cast<const bf16x8*>((const char*)As + byte);
      }
      #pragma unroll
      for (int ni = 0; ni < 4; ++ni) {
        int row = wc * 64 + ni * 16 + lc;
        int byte = row * 128 + ((kk * 64 + lr * 16) ^ ((row & 7) << 4));
        bfr[ni] = *reinterpret_cast<const bf16x8*>((const char*)Bs + byte);
      }
      #pragma unroll
      for (int mi = 0; mi < 4; ++mi)
        #pragma unroll
        for (int ni = 0; ni < 4; ++ni)
          acc[mi][ni] = __builtin_amdgcn_mfma_f32_16x16x32_bf16(
              af[mi], bfr[ni], acc[mi][ni], 0, 0, 0);
    }
    __syncthreads();
  }

  const int rB = mBase + wr * 64, cB = nBase + wc * 64;
  #pragma unroll
  for (int mi = 0; mi < 4; ++mi) {
    #pragma unroll
    for (int ni = 0; ni < 4; ++ni) {
      #pragma unroll
      for (int j2 = 0; j2 < 4; ++j2) {
        int r = rB + mi * 16 + lr * 4 + j2;
        int c = cB + ni * 16 + lc;
        float v = acc[mi][ni][j2];
        if (bias) v += bias[c];
        if constexpr (EPI == EPI_STORE) {
          outB[(size_t)r * N + c] = __float2bfloat16(v);
        } else if constexpr (EPI == EPI_GELU) {
          float e = __expf(1.5957691216057308f * v + 0.07135481627260086f * v * v * v);
          float t = 1.f - 2.f / (e + 1.f);
          outB[(size_t)r * N + c] = __float2bfloat16(0.5f * v * (1.f + t));
        } else if constexpr (EPI == EPI_PROJ) {
          int b = r >> 8;
          float g = ada[(size_t)b * 6144 + adaOff + c];
          float o = resid[(size_t)r * 1024 + c] + g * v;
          outF[(size_t)r * 1024 + c] = o;
          outB[(size_t)r * 1024 + c] = __float2bfloat16(o);
        } else if constexpr (EPI == EPI_OUT) {
          int b = r >> 8;
          float g = ada[(size_t)b * 6144 + adaOff + c];
          outF[(size_t)r * 1024 + c] = resid[(size_t)r * 1024 + c] + g * v;
        } else {
          if (r < 32) outF[(size_t)r * N + c] = v;
        }
      }
    }
  }
}

// ------------------------------------------------ 256^2 quadrant 8-phase GEMM
// (verified r9) 512 thr = 8 waves (2M x 4N), per-wave C = 128x64. BK=64.
template <int EPI>
__global__ __launch_bounds__(512, 1) void gemm8q(
    const bf16* __restrict__ A, const bf16* __restrict__ Bt,
    int N, int K, int gx, int grpG, int xcdP,
    const float* __restrict__ bias, bf16* __restrict__ outB) {
  __shared__ bf16 AS[2][2][128 * 64];              // 64 KB [par][half]
  __shared__ bf16 BS[2][2][128 * 64];              // 64 KB
  const int tid = threadIdx.x;
  const int w = tid >> 6, lane = tid & 63;
  const int wr = w >> 2, wc = w & 3;
  const int lr = lane >> 4, lc = lane & 15;

  const int flat = blockIdx.x;
  const int xcd = flat & 7, jj = flat >> 3;
  const int cpg = gx / grpG;
  const int grp = xcd / xcdP, par_ = xcd % xcdP;
  const int bx = grp * cpg + jj % cpg;
  const int by = (jj / cpg) * xcdP + par_;
  const int mBase = by * 256, nBase = bx * 256;
  const int nT = K >> 6;

  f32x4 acc[8][4];
  #pragma unroll
  for (int mi = 0; mi < 8; ++mi)
    #pragma unroll
    for (int ni = 0; ni < 4; ++ni) acc[mi][ni] = f32x4{0.f, 0.f, 0.f, 0.f};

  auto STAGE_A = [&](int th, int h) {
    if (th >= nT) return;
    const int k0 = th << 6;
    char* dst = (char*)&AS[th & 1][h][0];
    #pragma unroll
    for (int i = 0; i < 2; ++i) {
      int ck = i * 512 + tid;
      int rr = ck >> 3, c = ck & 7;
      int grow = mBase + (rr & 63) + ((rr >> 6) << 7) + h * 64;
      gload_lds16(A + (size_t)grow * K + k0 + ((c ^ (rr & 7)) << 3), dst + ck * 16);
    }
  };
  auto STAGE_B = [&](int th, int h) {
    if (th >= nT) return;
    const int k0 = th << 6;
    char* dst = (char*)&BS[th & 1][h][0];
    #pragma unroll
    for (int i = 0; i < 2; ++i) {
      int ck = i * 512 + tid;
      int rr = ck >> 3, c = ck & 7;
      int grow = nBase + ((rr >> 5) << 6) + h * 32 + (rr & 31);
      gload_lds16(Bt + (size_t)grow * K + k0 + ((c ^ (rr & 7)) << 3), dst + ck * 16);
    }
  };

  STAGE_A(0, 0); STAGE_A(0, 1); STAGE_B(0, 0); STAGE_B(0, 1);
  STAGE_A(1, 0); STAGE_A(1, 1);

  for (int t = 0; t < nT; ++t) {
    if (t == nT - 1) { asm volatile("s_waitcnt vmcnt(0)" ::: "memory"); }
    else             { asm volatile("s_waitcnt vmcnt(4)" ::: "memory"); }
    __builtin_amdgcn_s_barrier();

    const int p = t & 1;
    const char* A0 = (const char*)&AS[p][0][0];
    const char* A1 = (const char*)&AS[p][1][0];
    const char* B0 = (const char*)&BS[p][0][0];
    const char* B1 = (const char*)&BS[p][1][0];

    bf16x8 af0[2][4], af1[2][4], bf01[2][2], bf23[2][2];

    // ---- P0
    #pragma unroll
    for (int kk = 0; kk < 2; ++kk) {
      #pragma unroll
      for (int mi = 0; mi < 4; ++mi) {
        int rr = wr * 64 + mi * 16 + lc;
        af0[kk][mi] = *reinterpret_cast<const bf16x8*>(
            A0 + rr * 128 + ((kk * 64 + lr * 16) ^ ((rr & 7) << 4)));
      }
      #pragma unroll
      for (int ni = 0; ni < 2; ++ni) {
        int rr = wc * 32 + ni * 16 + lc;
        bf01[kk][ni] = *reinterpret_cast<const bf16x8*>(
            B0 + rr * 128 + ((kk * 64 + lr * 16) ^ ((rr & 7) << 4)));
      }
    }
    STAGE_B(t + 1, 0);
    __builtin_amdgcn_s_barrier();
    asm volatile("s_waitcnt lgkmcnt(0)" ::: "memory");
    __builtin_amdgcn_sched_barrier(0);
    __builtin_amdgcn_s_setprio(1);
    #pragma unroll
    for (int kk = 0; kk < 2; ++kk)
      #pragma unroll
      for (int mi = 0; mi < 4; ++mi)
        #pragma unroll
        for (int ni = 0; ni < 2; ++ni)
          acc[mi][ni] = __builtin_amdgcn_mfma_f32_16x16x32_bf16(
              af0[kk][mi], bf01[kk][ni], acc[mi][ni], 0, 0, 0);
    __builtin_amdgcn_s_setprio(0);
    __builtin_amdgcn_s_barrier();

    // ---- P1
    #pragma unroll
    for (int kk = 0; kk < 2; ++kk)
      #pragma unroll
      for (int ni = 0; ni < 2; ++ni) {
        int rr = wc * 32 + ni * 16 + lc;
        bf23[kk][ni] = *reinterpret_cast<const bf16x8*>(
            B1 + rr * 128 + ((kk * 64 + lr * 16) ^ ((rr & 7) << 4)));
      }
    STAGE_B(t + 1, 1);
    __builtin_amdgcn_s_barrier();
    asm volatile("s_waitcnt lgkmcnt(0)" ::: "memory");
    __builtin_amdgcn_sched_barrier(0);
    __builtin_amdgcn_s_setprio(1);
    #pragma unroll
    for (int kk = 0; kk < 2; ++kk)
      #pragma unroll
      for (int mi = 0; mi < 4; ++mi)
        #pragma unroll
        for (int ni = 0; ni < 2; ++ni)
          acc[mi][ni + 2] = __builtin_amdgcn_mfma_f32_16x16x32_bf16(
              af0[kk][mi], bf23[kk][ni], acc[mi][ni + 2], 0, 0, 0);
    __builtin_amdgcn_s_setprio(0);
    __builtin_amdgcn_s_barrier();

    // ---- P2
    #pragma unroll
    for (int kk = 0; kk < 2; ++kk)
      #pragma unroll
      for (int mi = 0; mi < 4; ++mi) {
        int rr = wr * 64 + mi * 16 + lc;
        af1[kk][mi] = *reinterpret_cast<const bf16x8*>(
            A1 + rr * 128 + ((kk * 64 + lr * 16) ^ ((rr & 7) << 4)));
      }
    STAGE_A(t + 2, 0);
    __builtin_amdgcn_s_barrier();
    asm volatile("s_waitcnt lgkmcnt(0)" ::: "memory");
    __builtin_amdgcn_sched_barrier(0);
    __builtin_amdgcn_s_setprio(1);
    #pragma unroll
    for (int kk = 0; kk < 2; ++kk)
      #pragma unroll
      for (int mi = 0; mi < 4; ++mi)
        #pragma unroll
        for (int ni = 0; ni < 2; ++ni)
          acc[mi + 4][ni] = __builtin_amdgcn_mfma_f32_16x16x32_bf16(
              af1[kk][mi], bf01[kk][ni], acc[mi + 4][ni], 0, 0, 0);
    __builtin_amdgcn_s_setprio(0);
    __builtin_amdgcn_s_barrier();

    // ---- P3
    STAGE_A(t + 2, 1);
    __builtin_amdgcn_s_barrier();
    __builtin_amdgcn_s_setprio(1);
    #pragma unroll
    for (int kk = 0; kk < 2; ++kk)
      #pragma unroll
      for (int mi = 0; mi < 4; ++mi)
        #pragma unroll
        for (int ni = 0; ni < 2; ++ni)
          acc[mi + 4][ni + 2] = __builtin_amdgcn_mfma_f32_16x16x32_bf16(
              af1[kk][mi], bf23[kk][ni], acc[mi + 4][ni + 2], 0, 0, 0);
    __builtin_amdgcn_s_setprio(0);
    __builtin_amdgcn_s_barrier();
  }

  const int rB = mBase + wr * 128, cB = nBase + wc * 64;
  #pragma unroll
  for (int mi = 0; mi < 8; ++mi) {
    #pragma unroll
    for (int ni = 0; ni < 4; ++ni) {
      #pragma unroll
      for (int j2 = 0; j2 < 4; ++j2) {
        int r = rB + mi * 16 + lr * 4 + j2;
        int c = cB + ni * 16 + lc;
        float v = acc[mi][ni][j2] + bias[c];
        if constexpr (EPI == EPI_STORE) {
          outB[(size_t)r * N + c] = __float2bfloat16(v);
        } else {  // EPI_GELU
          float e = __expf(1.5957691216057308f * v + 0.07135481627260086f * v * v * v);
          float t2 = 1.f - 2.f / (e + 1.f);
          outB[(size_t)r * N + c] = __float2bfloat16(0.5f * v * (1.f + t2));
        }
      }
    }
  }
}

// ------------------------------------------------ 256x128 quadrant 8-phase GEMM
// (verified r10) BN=128: per-wave C = 128x32 (acc[8][2]); vmcnt(2) boundary.
template <int EPI>
__global__ __launch_bounds__(512, 1) void gemm8q2(
    const bf16* __restrict__ A, const bf16* __restrict__ Bt,
    int N, int K, int gx, int grpG, int xcdP,
    const float* __restrict__ bias, const float* __restrict__ ada, int adaOff,
    const float* __restrict__ resid, float* __restrict__ outF,
    bf16* __restrict__ outB) {
  __shared__ bf16 AS[2][2][128 * 64];              // 64 KB
  __shared__ bf16 BS[2][2][64 * 64];               // 32 KB
  const int tid = threadIdx.x;
  const int w = tid >> 6, lane = tid & 63;
  const int wr = w >> 2, wc = w & 3;
  const int lr = lane >> 4, lc = lane & 15;

  const int flat = blockIdx.x;
  const int xcd = flat & 7, jj = flat >> 3;
  const int cpg = gx / grpG;
  const int grp = xcd / xcdP, par_ = xcd % xcdP;
  const int bx = grp * cpg + jj % cpg;
  const int by = (jj / cpg) * xcdP + par_;
  const int mBase = by * 256, nBase = bx * 128;
  const int nT = K >> 6;

  f32x4 acc[8][2];
  #pragma unroll
  for (int mi = 0; mi < 8; ++mi)
    #pragma unroll
    for (int ni = 0; ni < 2; ++ni) acc[mi][ni] = f32x4{0.f, 0.f, 0.f, 0.f};

  auto STAGE_A = [&](int th, int h) {
    if (th >= nT) return;
    const int k0 = th << 6;
    char* dst = (char*)&AS[th & 1][h][0];
    #pragma unroll
    for (int i = 0; i < 2; ++i) {
      int ck = i * 512 + tid;
      int rr = ck >> 3, c = ck & 7;
      int grow = mBase + (rr & 63) + ((rr >> 6) << 7) + h * 64;
      gload_lds16(A + (size_t)grow * K + k0 + ((c ^ (rr & 7)) << 3), dst + ck * 16);
    }
  };
  auto STAGE_B = [&](int th, int h) {
    if (th >= nT) return;
    const int k0 = th << 6;
    char* dst = (char*)&BS[th & 1][h][0];
    int ck = tid;
    int rr = ck >> 3, c = ck & 7;
    int grow = nBase + h * 64 + rr;
    gload_lds16(Bt + (size_t)grow * K + k0 + ((c ^ (rr & 7)) << 3), dst + ck * 16);
  };

  STAGE_A(0, 0); STAGE_A(0, 1); STAGE_B(0, 0); STAGE_B(0, 1);
  STAGE_A(1, 0); STAGE_A(1, 1);

  for (int t = 0; t < nT; ++t) {
    if (t == nT - 1)      { asm volatile("s_waitcnt vmcnt(0)" ::: "memory"); }
    else if (t == 0)      { asm volatile("s_waitcnt vmcnt(4)" ::: "memory"); }
    else                  { asm volatile("s_waitcnt vmcnt(2)" ::: "memory"); }
    __builtin_amdgcn_s_barrier();

    const int p = t & 1;
    const char* A0 = (const char*)&AS[p][0][0];
    const char* A1 = (const char*)&AS[p][1][0];
    const char* Bh = (const char*)&BS[p][wc >> 1][0];
    const int rbB = (wc & 1) * 32 + lc;            // + ni*16

    bf16x8 af0[2][4], af1[2][4], bfv[2][2];

    // ---- P0: read af0(8) + bfv(4); stage B(t+1,0); MFMA mi0-3 x kk0
    #pragma unroll
    for (int kk = 0; kk < 2; ++kk) {
      #pragma unroll
      for (int mi = 0; mi < 4; ++mi) {
        int rr = wr * 64 + mi * 16 + lc;
        af0[kk][mi] = *reinterpret_cast<const bf16x8*>(
            A0 + rr * 128 + ((kk * 64 + lr * 16) ^ ((rr & 7) << 4)));
      }
      #pragma unroll
      for (int ni = 0; ni < 2; ++ni) {
        int rr = rbB + ni * 16;
        bfv[kk][ni] = *reinterpret_cast<const bf16x8*>(
            Bh + rr * 128 + ((kk * 64 + lr * 16) ^ ((rr & 7) << 4)));
      }
    }
    STAGE_B(t + 1, 0);
    __builtin_amdgcn_s_barrier();
    asm volatile("s_waitcnt lgkmcnt(0)" ::: "memory");
    __builtin_amdgcn_sched_barrier(0);
    __builtin_amdgcn_s_setprio(1);
    #pragma unroll
    for (int mi = 0; mi < 4; ++mi)
      #pragma unroll
      for (int ni = 0; ni < 2; ++ni)
        acc[mi][ni] = __builtin_amdgcn_mfma_f32_16x16x32_bf16(
            af0[0][mi], bfv[0][ni], acc[mi][ni], 0, 0, 0);
    __builtin_amdgcn_s_setprio(0);
    __builtin_amdgcn_s_barrier();

    // ---- P1: stage A(t+2,0); MFMA mi0-3 x kk1 (register-only)
    STAGE_A(t + 2, 0);
    __builtin_amdgcn_s_barrier();
    __builtin_amdgcn_s_setprio(1);
    #pragma unroll
    for (int mi = 0; mi < 4; ++mi)
      #pragma unroll
      for (int ni = 0; ni < 2; ++ni)
        acc[mi][ni] = __builtin_amdgcn_mfma_f32_16x16x32_bf16(
            af0[1][mi], bfv[1][ni], acc[mi][ni], 0, 0, 0);
    __builtin_amdgcn_s_setprio(0);
    __builtin_amdgcn_s_barrier();

    // ---- P2: read af1(8); stage B(t+1,1); MFMA mi4-7 x kk0
    #pragma unroll
    for (int kk = 0; kk < 2; ++kk)
      #pragma unroll
      for (int mi = 0; mi < 4; ++mi) {
        int rr = wr * 64 + mi * 16 + lc;
        af1[kk][mi] = *reinterpret_cast<const bf16x8*>(
            A1 + rr * 128 + ((kk * 64 + lr * 16) ^ ((rr & 7) << 4)));
      }
    STAGE_B(t + 1, 1);
    __builtin_amdgcn_s_barrier();
    asm volatile("s_waitcnt lgkmcnt(0)" ::: "memory");
    __builtin_amdgcn_sched_barrier(0);
    __builtin_amdgcn_s_setprio(1);
    #pragma unroll
    for (int mi = 0; mi < 4; ++mi)
      #pragma unroll
      for (int ni = 0; ni < 2; ++ni)
        acc[mi + 4][ni] = __builtin_amdgcn_mfma_f32_16x16x32_bf16(
            af1[0][mi], bfv[0][ni], acc[mi + 4][ni], 0, 0, 0);
    __builtin_amdgcn_s_setprio(0);
    __builtin_amdgcn_s_barrier();

    // ---- P3: stage A(t+2,1); MFMA mi4-7 x kk1 (register-only)
    STAGE_A(t + 2, 1);
    __builtin_amdgcn_s_barrier();
    __builtin_amdgcn_s_setprio(1);
    #pragma unroll
    for (int mi = 0; mi < 4; ++mi)
      #pragma unroll
      for (int ni = 0; ni < 2; ++ni)
        acc[mi + 4][ni] = __builtin_amdgcn_mfma_f32_16x16x32_bf16(
            af1[1][mi], bfv[1][ni], acc[mi + 4][ni], 0, 0, 0);
    __builtin_amdgcn_s_setprio(0);
    __builtin_amdgcn_s_barrier();
  }

  const int rB = mBase + wr * 128, cB = nBase + wc * 32;
  #pragma unroll
  for (int mi = 0; mi < 8; ++mi) {
    #pragma unroll
    for (int ni = 0; ni < 2; ++ni) {
      #pragma unroll
      for (int j2 = 0; j2 < 4; ++j2) {
        int r = rB + mi * 16 + lr * 4 + j2;
        int c = cB + ni * 16 + lc;
        float v = acc[mi][ni][j2];
        if (bias) v += bias[c];
        if constexpr (EPI == EPI_STORE) {
          outB[(size_t)r * N + c] = __float2bfloat16(v);
        } else if constexpr (EPI == EPI_GELU) {
          float e = __expf(1.5957691216057308f * v + 0.07135481627260086f * v * v * v);
          float t2 = 1.f - 2.f / (e + 1.f);
          outB[(size_t)r * N + c] = __float2bfloat16(0.5f * v * (1.f + t2));
        } else if constexpr (EPI == EPI_PROJ) {
          int b = r >> 8;
          float g = ada[(size_t)b * 6144 + adaOff + c];
          float o = resid[(size_t)r * 1024 + c] + g * v;
          outF[(size_t)r * 1024 + c] = o;
          outB[(size_t)r * 1024 + c] = __float2bfloat16(o);
        } else if constexpr (EPI == EPI_OUT) {
          int b = r >> 8;
          float g = ada[(size_t)b * 6144 + adaOff + c];
          outF[(size_t)r * 1024 + c] = resid[(size_t)r * 1024 + c] + g * v;
        }
      }
    }
  }
}

// ------------------------------------------------ window attention (attn1, MFMA)
__global__ __launch_bounds__(512, 1) void attn1_mfma(
    const bf16* __restrict__ qkv, const float* __restrict__ rel,
    bf16* __restrict__ o) {
  __shared__ bf16 Ks[256 * 64];
  __shared__ bf16 Vt[64 * 256];
  __shared__ ushort Pl[8][32 * 40];
  __shared__ float bias_s[964];

  const int tid = threadIdx.x;
  const int w = tid >> 6, lane = tid & 63;
  const int p4 = lane >> 4, c = lane & 15;
  const int bh = blockIdx.x, b = bh >> 4, h = bh & 15;
  const bf16* basep = qkv + (size_t)b * 256 * 3072 + h * 64;

  #pragma unroll
  for (int it = 0; it < 4; ++it) {
    int t16 = it * 512 + tid;
    int row = t16 >> 3;
    int sc = ((t16 & 7) ^ (row & 7)) << 3;
    gload_lds16(basep + (size_t)row * 3072 + 1024 + sc, (char*)Ks + t16 * 16);
  }
  #pragma unroll
  for (int it = 0; it < 4; ++it) {
    int i = it * 512 + tid;
    int key = i >> 3, d0 = (i & 7) * 8;
    int4 u = *reinterpret_cast<const int4*>(basep + (size_t)key * 3072 + 2048 + d0);
    const ushort* us = reinterpret_cast<const ushort*>(&u);
    #pragma unroll
    for (int j = 0; j < 8; ++j) {
      int dh = d0 + j;
      int byte = dh * 512 + ((key * 2) ^ ((dh & 7) << 4));
      *reinterpret_cast<ushort*>((char*)Vt + byte) = us[j];
    }
  }
  for (int i = tid; i < 964; i += 512) bias_s[i] = rel[i * 16 + h];

  bf16x8 qf[2][2];
  #pragma unroll
  for (int mi = 0; mi < 2; ++mi)
    #pragma unroll
    for (int s = 0; s < 2; ++s) {
      int q = w * 32 + mi * 16 + c;
      int dh = s * 32 + p4 * 8;
      int4 u = *reinterpret_cast<const int4*>(basep + (size_t)q * 3072 + dh);
      uint32_t a[4] = {(uint32_t)u.x, (uint32_t)u.y, (uint32_t)u.z, (uint32_t)u.w};
      bf16x8 r;
      #pragma unroll
      for (int t = 0; t < 4; ++t) {
        float lo = __uint_as_float(a[t] << 16) * 0.125f;
        float hi = __uint_as_float(a[t] & 0xffff0000u) * 0.125f;
        r[2 * t]     = (short)(__float_as_uint(lo) >> 16);
        r[2 * t + 1] = (short)(__float_as_uint(hi) >> 16);
      }
      qf[mi][s] = r;
    }
  __syncthreads();

  float m_run[2][4], l_run[2][4];
  f32x4 oacc[2][4];
  #pragma unroll
  for (int mi = 0; mi < 2; ++mi)
    #pragma unroll
    for (int j = 0; j < 4; ++j) {
      m_run[mi][j] = -1e30f; l_run[mi][j] = 0.f;
      oacc[mi][j] = f32x4{0.f, 0.f, 0.f, 0.f};
    }

  ushort* Pw = &Pl[w][0];
  const int colterm = p4 * 4 - c + 15;

  for (int kt = 0; kt < 8; ++kt) {
    f32x4 sacc[2][2];
    #pragma unroll
    for (int mi = 0; mi < 2; ++mi)
      #pragma unroll
      for (int nf = 0; nf < 2; ++nf) {
        int bi = ((w * 2 + mi) - (kt * 2 + nf) + 15) * 31 + colterm;
        #pragma unroll
        for (int j = 0; j < 4; ++j) sacc[mi][nf][j] = bias_s[bi + j];
      }
    #pragma unroll
    for (int nf = 0; nf < 2; ++nf) {
      int key = kt * 32 + nf * 16 + c;
      #pragma unroll
      for (int s = 0; s < 2; ++s) {
        int byte = key * 128 + (((s * 4 + p4) ^ (key & 7)) << 4);
        bf16x8 kb = *reinterpret_cast<const bf16x8*>((const char*)Ks + byte);
        #pragma unroll
        for (int mi = 0; mi < 2; ++mi)
          sacc[mi][nf] = __builtin_amdgcn_mfma_f32_16x16x32_bf16(
              qf[mi][s], kb, sacc[mi][nf], 0, 0, 0);
      }
    }
    float sf[2][4];
    #pragma unroll
    for (int mi = 0; mi < 2; ++mi)
      #pragma unroll
      for (int j = 0; j < 4; ++j) {
        float cm = fmaxf(sacc[mi][0][j], sacc[mi][1][j]);
        cm = fmaxf(cm, __shfl_xor(cm, 1));
        cm = fmaxf(cm, __shfl_xor(cm, 2));
        cm = fmaxf(cm, __shfl_xor(cm, 4));
        cm = fmaxf(cm, __shfl_xor(cm, 8));
        float nm = fmaxf(m_run[mi][j], cm);
        sf[mi][j] = __expf(m_run[mi][j] - nm);
        m_run[mi][j] = nm;
        l_run[mi][j] *= sf[mi][j];
      }
    #pragma unroll
    for (int mi = 0; mi < 2; ++mi)
      #pragma unroll
      for (int nf = 0; nf < 4; ++nf)
        #pragma unroll
        for (int j = 0; j < 4; ++j) oacc[mi][nf][j] *= sf[mi][j];
    #pragma unroll
    for (int mi = 0; mi < 2; ++mi) {
      #pragma unroll
      for (int nf = 0; nf < 2; ++nf)
        #pragma unroll
        for (int j = 0; j < 4; ++j)
          sacc[mi][nf][j] = __expf(sacc[mi][nf][j] - m_run[mi][j]);
      #pragma unroll
      for (int j = 0; j < 4; ++j) {
        float lp = sacc[mi][0][j] + sacc[mi][1][j];
        lp += __shfl_xor(lp, 1);
        lp += __shfl_xor(lp, 2);
        lp += __shfl_xor(lp, 4);
        lp += __shfl_xor(lp, 8);
        l_run[mi][j] += lp;
      }
      #pragma unroll
      for (int nf = 0; nf < 2; ++nf)
        #pragma unroll
        for (int j = 0; j < 4; ++j)
          Pw[(mi * 16 + p4 * 4 + j) * 40 + nf * 16 + c] =
              f2bf_bits(sacc[mi][nf][j]);
    }
    bf16x8 pa[2], vb[4];
    #pragma unroll
    for (int mi = 0; mi < 2; ++mi)
      pa[mi] = *reinterpret_cast<const bf16x8*>(
          (const char*)Pw + (mi * 16 + c) * 80 + p4 * 16);
    #pragma unroll
    for (int nf = 0; nf < 4; ++nf) {
      int dh = nf * 16 + c;
      int byte = dh * 512 + (((kt * 4 + p4) ^ (dh & 7)) << 4);
      vb[nf] = *reinterpret_cast<const bf16x8*>((const char*)Vt + byte);
    }
    #pragma unroll
    for (int mi = 0; mi < 2; ++mi)
      #pragma unroll
      for (int nf = 0; nf < 4; ++nf)
        oacc[mi][nf] = __builtin_amdgcn_mfma_f32_16x16x32_bf16(
            pa[mi], vb[nf], oacc[mi][nf], 0, 0, 0);
  }

  #pragma unroll
  for (int mi = 0; mi < 2; ++mi) {
    float inv[4];
    #pragma unroll
    for (int j = 0; j < 4; ++j) inv[j] = 1.f / l_run[mi][j];
    #pragma unroll
    for (int nf = 0; nf < 4; ++nf)
      #pragma unroll
      for (int j = 0; j < 4; ++j) {
        int q = w * 32 + mi * 16 + p4 * 4 + j;
        int dh = nf * 16 + c;
        o[((size_t)b * 256 + q) * 1024 + h * 64 + dh] =
            __float2bfloat16(oacc[mi][nf][j] * inv[j]);
      }
  }
}

// ------------------------------------------------ cross attention (attn2, MFMA)
__global__ __launch_bounds__(512, 1) void attn2_mfma(
    const bf16* __restrict__ q2, const bf16* __restrict__ kv,
    bf16* __restrict__ o2) {
  __shared__ bf16 Ks[80 * 64];
  __shared__ bf16 Vt[64 * 128];
  __shared__ ushort Pl[8][32 * 104];

  const int tid = threadIdx.x;
  const int w = tid >> 6, lane = tid & 63;
  const int p4 = lane >> 4, c = lane & 15;
  const int bh = blockIdx.x, b = bh >> 4, h = bh & 15;
  const size_t kvrow0 = (size_t)b * 77;

  {
    int t16 = tid;
    int key = t16 >> 3;
    int sc = ((t16 & 7) ^ (key & 7)) << 3;
    gload_lds16(kv + (kvrow0 + key) * 2048 + h * 64 + sc, (char*)Ks + t16 * 16);
    if (tid < 128) {
      int u16 = 512 + tid; key = u16 >> 3;
      sc = ((u16 & 7) ^ (key & 7)) << 3;
      gload_lds16(kv + (kvrow0 + key) * 2048 + h * 64 + sc, (char*)Ks + u16 * 16);
    }
  }
  for (int i = tid; i < 80 * 8; i += 512) {
    int key = i >> 3, d0 = (i & 7) * 8;
    int4 u = *reinterpret_cast<const int4*>(
        kv + (kvrow0 + key) * 2048 + 1024 + h * 64 + d0);
    const ushort* us = reinterpret_cast<const ushort*>(&u);
    #pragma unroll
    for (int j = 0; j < 8; ++j) {
      int dh = d0 + j;
      int byte = dh * 256 + ((key * 2) ^ ((dh & 7) << 4));
      *reinterpret_cast<ushort*>((char*)Vt + byte) = us[j];
    }
  }
  {
    int row = lane >> 1, colb = 160 + (lane & 1) * 16;
    *reinterpret_cast<int4*>((char*)&Pl[w][0] + row * 208 + colb) =
        int4{0, 0, 0, 0};
  }
  bf16x8 qf[2][2];
  #pragma unroll
  for (int mi = 0; mi < 2; ++mi)
    #pragma unroll
    for (int s = 0; s < 2; ++s) {
      int q = w * 32 + mi * 16 + c;
      int dh = s * 32 + p4 * 8;
      int4 u = *reinterpret_cast<const int4*>(
          q2 + ((size_t)b * 256 + q) * 1024 + h * 64 + dh);
      uint32_t a[4] = {(uint32_t)u.x, (uint32_t)u.y, (uint32_t)u.z, (uint32_t)u.w};
      bf16x8 r;
      #pragma unroll
      for (int t = 0; t < 4; ++t) {
        float lo = __uint_as_float(a[t] << 16) * 0.125f;
        float hi = __uint_as_float(a[t] & 0xffff0000u) * 0.125f;
        r[2 * t]     = (short)(__float_as_uint(lo) >> 16);
        r[2 * t + 1] = (short)(__float_as_uint(hi) >> 16);
      }
      qf[mi][s] = r;
    }
  __syncthreads();

  f32x4 sacc[2][5];
  #pragma unroll
  for (int mi = 0; mi < 2; ++mi)
    #pragma unroll
    for (int nf = 0; nf < 5; ++nf)
      sacc[mi][nf] = f32x4{0.f, 0.f, 0.f, 0.f};
  #pragma unroll
  for (int nf = 0; nf < 5; ++nf) {
    int key = nf * 16 + c;
    #pragma unroll
    for (int s = 0; s < 2; ++s) {
      int byte = key * 128 + (((s * 4 + p4) ^ (key & 7)) << 4);
      bf16x8 kb = *reinterpret_cast<const bf16x8*>((const char*)Ks + byte);
      #pragma unroll
      for (int mi = 0; mi < 2; ++mi)
        sacc[mi][nf] = __builtin_amdgcn_mfma_f32_16x16x32_bf16(
            qf[mi][s], kb, sacc[mi][nf], 0, 0, 0);
    }
  }
  if (c >= 13) {
    #pragma unroll
    for (int mi = 0; mi < 2; ++mi)
      #pragma unroll
      for (int j = 0; j < 4; ++j) sacc[mi][4][j] = -1e30f;
  }
  float lrow[2][4];
  #pragma unroll
  for (int mi = 0; mi < 2; ++mi)
    #pragma unroll
    for (int j = 0; j < 4; ++j) {
      float cm = sacc[mi][0][j];
      #pragma unroll
      for (int nf = 1; nf < 5; ++nf) cm = fmaxf(cm, sacc[mi][nf][j]);
      cm = fmaxf(cm, __shfl_xor(cm, 1));
      cm = fmaxf(cm, __shfl_xor(cm, 2));
      cm = fmaxf(cm, __shfl_xor(cm, 4));
      cm = fmaxf(cm, __shfl_xor(cm, 8));
      float lp = 0.f;
      #pragma unroll
      for (int nf = 0; nf < 5; ++nf) {
        sacc[mi][nf][j] = __expf(sacc[mi][nf][j] - cm);
        lp += sacc[mi][nf][j];
      }
      lp += __shfl_xor(lp, 1);
      lp += __shfl_xor(lp, 2);
      lp += __shfl_xor(lp, 4);
      lp += __shfl_xor(lp, 8);
      lrow[mi][j] = lp;
    }
  ushort* Pw = &Pl[w][0];
  #pragma unroll
  for (int mi = 0; mi < 2; ++mi)
    #pragma unroll
    for (int nf = 0; nf < 5; ++nf)
      #pragma unroll
      for (int j = 0; j < 4; ++j)
        Pw[(mi * 16 + p4 * 4 + j) * 104 + nf * 16 + c] =
            f2bf_bits(sacc[mi][nf][j]);
  f32x4 oacc[2][4];
  #pragma unroll
  for (int mi = 0; mi < 2; ++mi)
    #pragma unroll
    for (int nf = 0; nf < 4; ++nf) oacc[mi][nf] = f32x4{0.f, 0.f, 0.f, 0.f};
  #pragma unroll
  for (int kk = 0; kk < 3; ++kk) {
    bf16x8 pa[2], vb[4];
    #pragma unroll
    for (int mi = 0; mi < 2; ++mi)
      pa[mi] = *reinterpret_cast<const bf16x8*>(
          (const char*)Pw + (mi * 16 + c) * 208 + kk * 64 + p4 * 16);
    #pragma unroll
    for (int nf = 0; nf < 4; ++nf) {
      int dh = nf * 16 + c;
      int byte = dh * 256 + (((kk * 4 + p4) ^ (dh & 7)) << 4);
      vb[nf] = *reinterpret_cast<const bf16x8*>((const char*)Vt + byte);
    }
    #pragma unroll
    for (int mi = 0; mi < 2; ++mi)
      #pragma unroll
      for (int nf = 0; nf < 4; ++nf)
        oacc[mi][nf] = __builtin_amdgcn_mfma_f32_16x16x32_bf16(
            pa[mi], vb[nf], oacc[mi][nf], 0, 0, 0);
  }
  #pragma unroll
  for (int mi = 0; mi < 2; ++mi) {
    float inv[4];
    #pragma unroll
    for (int j = 0; j < 4; ++j) inv[j] = 1.f / lrow[mi][j];
    #pragma unroll
    for (int nf = 0; nf < 4; ++nf)
      #pragma unroll
      for (int j = 0; j < 4; ++j) {
        int q = w * 32 + mi * 16 + p4 * 4 + j;
        int dh = nf * 16 + c;
        o2[((size_t)b * 256 + q) * 1024 + h * 64 + dh] =
            __float2bfloat16(oacc[mi][nf][j] * inv[j]);
      }
  }
}

// ------------------------------------------------ o2 head-major -> xcur += (d*16+h)
__global__ __launch_bounds__(256) void permute_add(
    const bf16* __restrict__ o2, float* __restrict__ xcur) {
  __shared__ float s_lds[1088];
  const int tid = threadIdx.x;
  const int row0 = blockIdx.x * 4;
  for (int r = 0; r < 4; ++r) {
    const int row = row0 + r;
    #pragma unroll
    for (int i = 0; i < 4; ++i) {
      int cc = i * 256 + tid;
      float v = __bfloat162float(o2[(size_t)row * 1024 + cc]);
      s_lds[cc + (cc >> 4)] = v;
    }
    __syncthreads();
    float4 add;
    #pragma unroll
    for (int t = 0; t < 4; ++t) {
      int ct = tid * 4 + t;
      int src = (ct & 15) * 64 + (ct >> 4);
      (&add.x)[t] = s_lds[src + (src >> 4)];
    }
    float4* xp = reinterpret_cast<float4*>(xcur + (size_t)row * 1024 + tid * 4);
    float4 cur = *xp;
    cur.x += add.x; cur.y += add.y; cur.z += add.z; cur.w += add.w;
    *xp = cur;
    __syncthreads();
  }
}

// ---------------------------------------------------------------- launcher

extern "C" void kernel_launch(void* const* d_in, const int* in_sizes, int n_in,
                              void* d_out, int out_size, void* d_ws, size_t ws_size,
                              hipStream_t stream) {
  (void)in_sizes; (void)n_in; (void)out_size; (void)ws_size;
  const float* x      = (const float*)d_in[0];
  const float* noise  = (const float*)d_in[1];
  const float* y      = (const float*)d_in[2];
  const float* W_qkv  = (const float*)d_in[3];
  const float* b_qkv  = (const float*)d_in[4];
  const float* W_proj = (const float*)d_in[5];
  const float* b_proj = (const float*)d_in[6];
  const float* rel    = (const float*)d_in[7];
  const float* W_ada  = (const float*)d_in[8];
  const float* b_ada  = (const float*)d_in[9];
  const float* W_fc1  = (const float*)d_in[10];
  const float* b_fc1  = (const float*)d_in[11];
  const float* W_fc2  = (const float*)d_in[12];
  const float* b_fc2  = (const float*)d_in[13];
  const float* W_q    = (const float*)d_in[14];
  const float* W_kv   = (const float*)d_in[15];

  char* ws = (char*)d_ws;
  size_t off = 0;
  auto alloc = [&](size_t bytes) {
    char* p = ws + off;
    off = (off + bytes + 255) & ~(size_t)255;
    return p;
  };
  float* ada   = (float*)alloc(32u * 6144 * 4);
  float* xcur  = (float*)alloc(8192u * 1024 * 4);
  bf16* WqkvT  = (bf16*)alloc(3072u * 1024 * 2);
  bf16* WprojT = (bf16*)alloc(1024u * 1024 * 2);
  bf16* WqT    = (bf16*)alloc(1024u * 1024 * 2);
  bf16* WkvT   = (bf16*)alloc(2048u * 1024 * 2);
  bf16* Wfc1T  = (bf16*)alloc(4096u * 1024 * 2);
  bf16* Wfc2T  = (bf16*)alloc(1024u * 4096 * 2);
  bf16* WadaT  = (bf16*)alloc(6144u * 1024 * 2);
  bf16* Apad   = (bf16*)alloc(128u * 1024 * 2);
  bf16* hbuf   = (bf16*)alloc(8192u * 1024 * 2);
  bf16* big    = (bf16*)alloc(8192u * 4096 * 2);
  bf16* obuf   = (bf16*)alloc(8192u * 1024 * 2);
  bf16* kvbuf  = (bf16*)alloc(2560u * 2048 * 2);
  bf16* ybuf   = (bf16*)alloc(2560u * 1024 * 2);
  float* outF  = (float*)d_out;

  // weight prep (W_q / W_kv get head-major column permutation)
  transpose_bf16<0><<<dim3(96, 32), 256, 0, stream>>>(W_qkv, WqkvT, 1024, 3072);
  transpose_bf16<0><<<dim3(32, 32), 256, 0, stream>>>(W_proj, WprojT, 1024, 1024);
  transpose_bf16<1><<<dim3(32, 32), 256, 0, stream>>>(W_q, WqT, 1024, 1024);
  transpose_bf16<2><<<dim3(64, 32), 256, 0, stream>>>(W_kv, WkvT, 1024, 2048);
  transpose_bf16<0><<<dim3(128, 32), 256, 0, stream>>>(W_fc1, Wfc1T, 1024, 4096);
  transpose_bf16<0><<<dim3(32, 128), 256, 0, stream>>>(W_fc2, Wfc2T, 4096, 1024);
  transpose_bf16<0><<<dim3(192, 32), 256, 0, stream>>>(W_ada, WadaT, 1024, 6144);
  conv_y<<<2560 * 1024 / 256, 256, 0, stream>>>(y, ybuf);

  // ada = silu(noise) @ W_ada + b_ada (M=32 padded to 128)
  silu_pad<<<512, 256, 0, stream>>>(noise, Apad);
  gemm_bf16<EPI_ADAF><<<48, 256, 0, stream>>>(
      Apad, WadaT, 6144, 1024, 48, 8, 1, b_ada, nullptr, 0, nullptr, ada, nullptr);

  // MSA branch
  ln_mod<<<8192, 256, 0, stream>>>(x, ada, 0, 1024, hbuf);
  gemm8q<EPI_STORE><<<384, 512, 0, stream>>>(            // qkv: 12x32 tiles 256^2
      hbuf, WqkvT, 3072, 1024, 12, 4, 2, b_qkv, big);
  attn1_mfma<<<512, 512, 0, stream>>>(big, rel, obuf);
  gemm8q2<EPI_PROJ><<<256, 512, 0, stream>>>(            // proj: 1-XCD-per-row-panel
      obuf, WprojT, 1024, 1024, 8, 1, 8, b_proj, ada, 2048, x, xcur, hbuf);

  // cross-attention branch (head-major q2/kv)
  gemm8q2<EPI_STORE><<<256, 512, 0, stream>>>(           // q2
      hbuf, WqT, 1024, 1024, 8, 1, 8, nullptr, nullptr, 0, nullptr, nullptr, obuf);
  gemm_bf16<EPI_STORE><<<320, 256, 0, stream>>>(         // kv: 16x20 tiles 128^2
      ybuf, WkvT, 2048, 1024, 16, 8, 1, nullptr, nullptr, 0, nullptr, nullptr, kvbuf);
  attn2_mfma<<<512, 512, 0, stream>>>(obuf, kvbuf, big);
  permute_add<<<2048, 256, 0, stream>>>(big, xcur);

  // MLP branch
  ln_mod<<<8192, 256, 0, stream>>>(xcur, ada, 3072, 4096, hbuf);
  gemm8q<EPI_GELU><<<512, 512, 0, stream>>>(             // fc1: 16x32 tiles 256^2
      hbuf, Wfc1T, 4096, 1024, 16, 4, 2, b_fc1, big);
  gemm8q2<EPI_OUT><<<256, 512, 0, stream>>>(             // fc2: 1-XCD-per-row-panel
      big, Wfc2T, 1024, 4096, 8, 1, 8, b_fc2, ada, 5120, xcur, outF, nullptr);
}

// Round 12
// 491.531 us; speedup vs baseline: 1.0709x; 1.0520x over previous
//
#include <hip/hip_runtime.h>
#include <hip/hip_bf16.h>
#include <stdint.h>

typedef __hip_bfloat16 bf16;
using bf16x8 = __attribute__((ext_vector_type(8))) short;   // 8 bf16 (4 VGPRs)
using f32x4  = __attribute__((ext_vector_type(4))) float;   // 4 fp32

// ---------------------------------------------------------------- utilities

__device__ __forceinline__ void gload_lds16(const void* g, void* l) {
  using gchar = __attribute__((address_space(1))) char;
  using lchar = __attribute__((address_space(3))) char;
  gchar* gp = reinterpret_cast<gchar*>(reinterpret_cast<uintptr_t>(g));
  lchar* lp = reinterpret_cast<lchar*>(static_cast<uint32_t>(reinterpret_cast<uintptr_t>(l)));
  __builtin_amdgcn_global_load_lds(gp, lp, 16, 0, 0);
}

__device__ __forceinline__ unsigned short f2bf_bits(float x) {
  uint32_t u = __float_as_uint(x);
  uint32_t r = (u + 0x7fffu + ((u >> 16) & 1u)) >> 16;
  return (unsigned short)r;
}

// ------------------------------------------------ fused prep: 7 transposes +
// y->bf16 (pad 2560) + silu(noise)->bf16 (pad 128) in ONE launch.
// Transposes: W (K x N fp32) -> Wt (N x K bf16), optional head-major perm.
__global__ __launch_bounds__(256) void prep_all(
    const float* __restrict__ Wqkv, const float* __restrict__ Wproj,
    const float* __restrict__ Wq, const float* __restrict__ Wkv,
    const float* __restrict__ Wfc1, const float* __restrict__ Wfc2,
    const float* __restrict__ Wada, const float* __restrict__ y,
    const float* __restrict__ noise,
    bf16* __restrict__ WqkvT, bf16* __restrict__ WprojT,
    bf16* __restrict__ WqT, bf16* __restrict__ WkvT,
    bf16* __restrict__ Wfc1T, bf16* __restrict__ Wfc2T,
    bf16* __restrict__ WadaT, bf16* __restrict__ yb, bf16* __restrict__ Apad) {
  __shared__ float t[32][33];
  const int tid = threadIdx.x;
  int bid = blockIdx.x;

  const float* W = nullptr; bf16* Wt = nullptr;
  int K = 0, N = 0, nx = 0, perm = 0;
  if (bid < 3072)        { W = Wqkv;  Wt = WqkvT;  K = 1024; N = 3072; nx = 96;  perm = 0; }
  else if (bid < 4096)   { bid -= 3072;  W = Wproj; Wt = WprojT; K = 1024; N = 1024; nx = 32;  perm = 0; }
  else if (bid < 5120)   { bid -= 4096;  W = Wq;    Wt = WqT;    K = 1024; N = 1024; nx = 32;  perm = 1; }
  else if (bid < 7168)   { bid -= 5120;  W = Wkv;   Wt = WkvT;   K = 1024; N = 2048; nx = 64;  perm = 2; }
  else if (bid < 11264)  { bid -= 7168;  W = Wfc1;  Wt = Wfc1T;  K = 1024; N = 4096; nx = 128; perm = 0; }
  else if (bid < 15360)  { bid -= 11264; W = Wfc2;  Wt = Wfc2T;  K = 4096; N = 1024; nx = 32;  perm = 0; }
  else if (bid < 21504)  { bid -= 15360; W = Wada;  Wt = WadaT;  K = 1024; N = 6144; nx = 192; perm = 0; }
  else if (bid < 31744) {                // conv_y: 10240 blocks
    bid -= 21504;
    int i = bid * 256 + tid;
    float v = (i < 2464 * 1024) ? y[i] : 0.f;
    yb[i] = __float2bfloat16(v);
    return;
  } else {                               // silu_pad: 512 blocks
    bid -= 31744;
    int i = bid * 256 + tid;
    float v = 0.f;
    if (i < 32 * 1024) {
      float xx = noise[i];
      v = xx / (1.f + __expf(-xx));
    }
    Apad[i] = __float2bfloat16(v);
    return;
  }

  const int n0 = (bid % nx) * 32, k0 = (bid / nx) * 32;
  const int tx = tid & 31, ty = tid >> 5;
  #pragma unroll
  for (int i = ty; i < 32; i += 8) t[i][tx] = W[(size_t)(k0 + i) * N + n0 + tx];
  __syncthreads();
  #pragma unroll
  for (int i = ty; i < 32; i += 8) {
    int n = n0 + i;
    int np;
    if (perm == 0) np = n;
    else if (perm == 1) np = (n & 15) * 64 + (n >> 4);
    else { int base = n & 1024, m = n & 1023; np = base + (m & 15) * 64 + (m >> 4); }
    Wt[(size_t)np * K + k0 + tx] = __float2bfloat16(t[tx][i]);
  }
}

// ------------------------------------------------ LN + modulate -> bf16
__global__ __launch_bounds__(256) void ln_mod(
    const float* __restrict__ x, const float* __restrict__ ada,
    int shOff, int scOff, bf16* __restrict__ out) {
  const int row = blockIdx.x, b = row >> 8, tid = threadIdx.x;
  const float* xr = x + (size_t)row * 1024;
  float v[4], s = 0.f, ss = 0.f;
  #pragma unroll
  for (int i = 0; i < 4; ++i) {
    v[i] = xr[tid + i * 256];
    s += v[i]; ss += v[i] * v[i];
  }
  #pragma unroll
  for (int o = 32; o; o >>= 1) { s += __shfl_xor(s, o); ss += __shfl_xor(ss, o); }
  __shared__ float red[8];
  const int w = tid >> 6;
  if ((tid & 63) == 0) { red[w] = s; red[w + 4] = ss; }
  __syncthreads();
  s = red[0] + red[1] + red[2] + red[3];
  ss = red[4] + red[5] + red[6] + red[7];
  float mu = s * (1.f / 1024.f);
  float var = ss * (1.f / 1024.f) - mu * mu;
  float rstd = rsqrtf(var + 1e-6f);
  const float* adab = ada + (size_t)b * 6144;
  #pragma unroll
  for (int i = 0; i < 4; ++i) {
    int c = tid + i * 256;
    float o = (v[i] - mu) * rstd * (1.f + adab[scOff + c]) + adab[shOff + c];
    out[(size_t)row * 1024 + c] = __float2bfloat16(o);
  }
}

// ------------------------------------------------ fused o2-permute-add + LN+mod
// xcur[row] += perm(o2[row]); out = modulate(LN(xcur[row])); xcur updated.
__global__ __launch_bounds__(256) void permute_ln(
    const bf16* __restrict__ o2, float* __restrict__ xcur,
    const float* __restrict__ ada, int shOff, int scOff,
    bf16* __restrict__ out) {
  __shared__ float s_lds[1088];
  __shared__ float red[8];
  const int row = blockIdx.x, b = row >> 8, tid = threadIdx.x;
  #pragma unroll
  for (int i = 0; i < 4; ++i) {
    int hm = i * 256 + tid;
    float v = __bfloat162float(o2[(size_t)row * 1024 + hm]);
    s_lds[hm + (hm >> 4)] = v;
  }
  __syncthreads();
  float v[4], s = 0.f, ss = 0.f;
  float4* xp = reinterpret_cast<float4*>(xcur + (size_t)row * 1024 + tid * 4);
  float4 cur = *xp;
  #pragma unroll
  for (int tI = 0; tI < 4; ++tI) {
    int c = tid * 4 + tI;
    int src = (c & 15) * 64 + (c >> 4);
    float xv = (&cur.x)[tI] + s_lds[src + (src >> 4)];
    v[tI] = xv; s += xv; ss += xv * xv;
  }
  float4 nw; nw.x = v[0]; nw.y = v[1]; nw.z = v[2]; nw.w = v[3];
  *xp = nw;
  #pragma unroll
  for (int o = 32; o; o >>= 1) { s += __shfl_xor(s, o); ss += __shfl_xor(ss, o); }
  const int w = tid >> 6;
  if ((tid & 63) == 0) { red[w] = s; red[w + 4] = ss; }
  __syncthreads();
  s = red[0] + red[1] + red[2] + red[3];
  ss = red[4] + red[5] + red[6] + red[7];
  float mu = s * (1.f / 1024.f);
  float var = ss * (1.f / 1024.f) - mu * mu;
  float rstd = rsqrtf(var + 1e-6f);
  const float* adab = ada + (size_t)b * 6144;
  #pragma unroll
  for (int tI = 0; tI < 4; ++tI) {
    int c = tid * 4 + tI;
    float o = (v[tI] - mu) * rstd * (1.f + adab[scOff + c]) + adab[shOff + c];
    out[(size_t)row * 1024 + c] = __float2bfloat16(o);
  }
}

// ------------------------------------------------ generic bf16 MFMA GEMM (128^2)
enum { EPI_STORE = 0, EPI_GELU = 1, EPI_PROJ = 2, EPI_OUT = 3, EPI_ADAF = 4 };

template <int EPI>
__global__ __launch_bounds__(256, 2) void gemm_bf16(
    const bf16* __restrict__ A, const bf16* __restrict__ Bt,
    int N, int K, int gx, int grpG, int xcdP,
    const float* __restrict__ bias, const float* __restrict__ ada, int adaOff,
    const float* __restrict__ resid, float* __restrict__ outF,
    bf16* __restrict__ outB) {
  __shared__ bf16 As[128 * 64];
  __shared__ bf16 Bs[128 * 64];
  const int tid = threadIdx.x;
  const int w = tid >> 6, lane = tid & 63;
  const int wr = w >> 1, wc = w & 1;
  const int lr = lane >> 4, lc = lane & 15;

  const int flat = blockIdx.x;
  const int xcd = flat & 7, j = flat >> 3;
  const int cpg = gx / grpG;
  const int grp = xcd / xcdP, par = xcd % xcdP;
  const int bx = grp * cpg + j % cpg;
  const int by = (j / cpg) * xcdP + par;
  const int mBase = by * 128, nBase = bx * 128;

  f32x4 acc[4][4];
  #pragma unroll
  for (int mi = 0; mi < 4; ++mi)
    #pragma unroll
    for (int ni = 0; ni < 4; ++ni)
      #pragma unroll
      for (int j2 = 0; j2 < 4; ++j2) acc[mi][ni][j2] = 0.f;

  const int nK = K >> 6;
  for (int ks = 0; ks < nK; ++ks) {
    const int k0 = ks << 6;
    #pragma unroll
    for (int i = 0; i < 4; ++i) {
      int t16 = w * 256 + i * 64 + lane;
      int row = t16 >> 3;
      int cL = ((t16 & 7) ^ (row & 7)) << 3;
      gload_lds16(A + (size_t)(mBase + row) * K + k0 + cL, (char*)As + t16 * 16);
      gload_lds16(Bt + (size_t)(nBase + row) * K + k0 + cL, (char*)Bs + t16 * 16);
    }
    __syncthreads();
    #pragma unroll
    for (int kk = 0; kk < 2; ++kk) {
      bf16x8 af[4], bfr[4];
      #pragma unroll
      for (int mi = 0; mi < 4; ++mi) {
        int row = wr * 64 + mi * 16 + lc;
        int byte = row * 128 + ((kk * 64 + lr * 16) ^ ((row & 7) << 4));
        af[mi] = *reinterpret_cast<const bf16x8*>((const char*)As + byte);
      }
      #pragma unroll
      for (int ni = 0; ni < 4; ++ni) {
        int row = wc * 64 + ni * 16 + lc;
        int byte = row * 128 + ((kk * 64 + lr * 16) ^ ((row & 7) << 4));
        bfr[ni] = *reinterpret_cast<const bf16x8*>((const char*)Bs + byte);
      }
      #pragma unroll
      for (int mi = 0; mi < 4; ++mi)
        #pragma unroll
        for (int ni = 0; ni < 4; ++ni)
          acc[mi][ni] = __builtin_amdgcn_mfma_f32_16x16x32_bf16(
              af[mi], bfr[ni], acc[mi][ni], 0, 0, 0);
    }
    __syncthreads();
  }

  const int rB = mBase + wr * 64, cB = nBase + wc * 64;
  #pragma unroll
  for (int mi = 0; mi < 4; ++mi) {
    #pragma unroll
    for (int ni = 0; ni < 4; ++ni) {
      #pragma unroll
      for (int j2 = 0; j2 < 4; ++j2) {
        int r = rB + mi * 16 + lr * 4 + j2;
        int c = cB + ni * 16 + lc;
        float v = acc[mi][ni][j2];
        if (bias) v += bias[c];
        if constexpr (EPI == EPI_STORE) {
          outB[(size_t)r * N + c] = __float2bfloat16(v);
        } else if constexpr (EPI == EPI_GELU) {
          float e = __expf(1.5957691216057308f * v + 0.07135481627260086f * v * v * v);
          float t = 1.f - 2.f / (e + 1.f);
          outB[(size_t)r * N + c] = __float2bfloat16(0.5f * v * (1.f + t));
        } else if constexpr (EPI == EPI_PROJ) {
          int b = r >> 8;
          float g = ada[(size_t)b * 6144 + adaOff + c];
          float o = resid[(size_t)r * 1024 + c] + g * v;
          outF[(size_t)r * 1024 + c] = o;
          outB[(size_t)r * 1024 + c] = __float2bfloat16(o);
        } else if constexpr (EPI == EPI_OUT) {
          int b = r >> 8;
          float g = ada[(size_t)b * 6144 + adaOff + c];
          outF[(size_t)r * 1024 + c] = resid[(size_t)r * 1024 + c] + g * v;
        } else {
          if (r < 32) outF[(size_t)r * N + c] = v;
        }
      }
    }
  }
}

// ------------------------------------------------ 256^2 quadrant 8-phase GEMM
// (verified r9) 512 thr = 8 waves (2M x 4N), per-wave C = 128x64. BK=64.
template <int EPI>
__global__ __launch_bounds__(512, 1) void gemm8q(
    const bf16* __restrict__ A, const bf16* __restrict__ Bt,
    int N, int K, int gx, int grpG, int xcdP,
    const float* __restrict__ bias, bf16* __restrict__ outB) {
  __shared__ bf16 AS[2][2][128 * 64];              // 64 KB [par][half]
  __shared__ bf16 BS[2][2][128 * 64];              // 64 KB
  const int tid = threadIdx.x;
  const int w = tid >> 6, lane = tid & 63;
  const int wr = w >> 2, wc = w & 3;
  const int lr = lane >> 4, lc = lane & 15;

  const int flat = blockIdx.x;
  const int xcd = flat & 7, jj = flat >> 3;
  const int cpg = gx / grpG;
  const int grp = xcd / xcdP, par_ = xcd % xcdP;
  const int bx = grp * cpg + jj % cpg;
  const int by = (jj / cpg) * xcdP + par_;
  const int mBase = by * 256, nBase = bx * 256;
  const int nT = K >> 6;

  f32x4 acc[8][4];
  #pragma unroll
  for (int mi = 0; mi < 8; ++mi)
    #pragma unroll
    for (int ni = 0; ni < 4; ++ni) acc[mi][ni] = f32x4{0.f, 0.f, 0.f, 0.f};

  auto STAGE_A = [&](int th, int h) {
    if (th >= nT) return;
    const int k0 = th << 6;
    char* dst = (char*)&AS[th & 1][h][0];
    #pragma unroll
    for (int i = 0; i < 2; ++i) {
      int ck = i * 512 + tid;
      int rr = ck >> 3, c = ck & 7;
      int grow = mBase + (rr & 63) + ((rr >> 6) << 7) + h * 64;
      gload_lds16(A + (size_t)grow * K + k0 + ((c ^ (rr & 7)) << 3), dst + ck * 16);
    }
  };
  auto STAGE_B = [&](int th, int h) {
    if (th >= nT) return;
    const int k0 = th << 6;
    char* dst = (char*)&BS[th & 1][h][0];
    #pragma unroll
    for (int i = 0; i < 2; ++i) {
      int ck = i * 512 + tid;
      int rr = ck >> 3, c = ck & 7;
      int grow = nBase + ((rr >> 5) << 6) + h * 32 + (rr & 31);
      gload_lds16(Bt + (size_t)grow * K + k0 + ((c ^ (rr & 7)) << 3), dst + ck * 16);
    }
  };

  STAGE_A(0, 0); STAGE_A(0, 1); STAGE_B(0, 0); STAGE_B(0, 1);
  STAGE_A(1, 0); STAGE_A(1, 1);

  for (int t = 0; t < nT; ++t) {
    if (t == nT - 1) { asm volatile("s_waitcnt vmcnt(0)" ::: "memory"); }
    else             { asm volatile("s_waitcnt vmcnt(4)" ::: "memory"); }
    __builtin_amdgcn_s_barrier();

    const int p = t & 1;
    const char* A0 = (const char*)&AS[p][0][0];
    const char* A1 = (const char*)&AS[p][1][0];
    const char* B0 = (const char*)&BS[p][0][0];
    const char* B1 = (const char*)&BS[p][1][0];

    bf16x8 af0[2][4], af1[2][4], bf01[2][2], bf23[2][2];

    // ---- P0
    #pragma unroll
    for (int kk = 0; kk < 2; ++kk) {
      #pragma unroll
      for (int mi = 0; mi < 4; ++mi) {
        int rr = wr * 64 + mi * 16 + lc;
        af0[kk][mi] = *reinterpret_cast<const bf16x8*>(
            A0 + rr * 128 + ((kk * 64 + lr * 16) ^ ((rr & 7) << 4)));
      }
      #pragma unroll
      for (int ni = 0; ni < 2; ++ni) {
        int rr = wc * 32 + ni * 16 + lc;
        bf01[kk][ni] = *reinterpret_cast<const bf16x8*>(
            B0 + rr * 128 + ((kk * 64 + lr * 16) ^ ((rr & 7) << 4)));
      }
    }
    STAGE_B(t + 1, 0);
    __builtin_amdgcn_s_barrier();
    asm volatile("s_waitcnt lgkmcnt(0)" ::: "memory");
    __builtin_amdgcn_sched_barrier(0);
    __builtin_amdgcn_s_setprio(1);
    #pragma unroll
    for (int kk = 0; kk < 2; ++kk)
      #pragma unroll
      for (int mi = 0; mi < 4; ++mi)
        #pragma unroll
        for (int ni = 0; ni < 2; ++ni)
          acc[mi][ni] = __builtin_amdgcn_mfma_f32_16x16x32_bf16(
              af0[kk][mi], bf01[kk][ni], acc[mi][ni], 0, 0, 0);
    __builtin_amdgcn_s_setprio(0);
    __builtin_amdgcn_s_barrier();

    // ---- P1
    #pragma unroll
    for (int kk = 0; kk < 2; ++kk)
      #pragma unroll
      for (int ni = 0; ni < 2; ++ni) {
        int rr = wc * 32 + ni * 16 + lc;
        bf23[kk][ni] = *reinterpret_cast<const bf16x8*>(
            B1 + rr * 128 + ((kk * 64 + lr * 16) ^ ((rr & 7) << 4)));
      }
    STAGE_B(t + 1, 1);
    __builtin_amdgcn_s_barrier();
    asm volatile("s_waitcnt lgkmcnt(0)" ::: "memory");
    __builtin_amdgcn_sched_barrier(0);
    __builtin_amdgcn_s_setprio(1);
    #pragma unroll
    for (int kk = 0; kk < 2; ++kk)
      #pragma unroll
      for (int mi = 0; mi < 4; ++mi)
        #pragma unroll
        for (int ni = 0; ni < 2; ++ni)
          acc[mi][ni + 2] = __builtin_amdgcn_mfma_f32_16x16x32_bf16(
              af0[kk][mi], bf23[kk][ni], acc[mi][ni + 2], 0, 0, 0);
    __builtin_amdgcn_s_setprio(0);
    __builtin_amdgcn_s_barrier();

    // ---- P2
    #pragma unroll
    for (int kk = 0; kk < 2; ++kk)
      #pragma unroll
      for (int mi = 0; mi < 4; ++mi) {
        int rr = wr * 64 + mi * 16 + lc;
        af1[kk][mi] = *reinterpret_cast<const bf16x8*>(
            A1 + rr * 128 + ((kk * 64 + lr * 16) ^ ((rr & 7) << 4)));
      }
    STAGE_A(t + 2, 0);
    __builtin_amdgcn_s_barrier();
    asm volatile("s_waitcnt lgkmcnt(0)" ::: "memory");
    __builtin_amdgcn_sched_barrier(0);
    __builtin_amdgcn_s_setprio(1);
    #pragma unroll
    for (int kk = 0; kk < 2; ++kk)
      #pragma unroll
      for (int mi = 0; mi < 4; ++mi)
        #pragma unroll
        for (int ni = 0; ni < 2; ++ni)
          acc[mi + 4][ni] = __builtin_amdgcn_mfma_f32_16x16x32_bf16(
              af1[kk][mi], bf01[kk][ni], acc[mi + 4][ni], 0, 0, 0);
    __builtin_amdgcn_s_setprio(0);
    __builtin_amdgcn_s_barrier();

    // ---- P3
    STAGE_A(t + 2, 1);
    __builtin_amdgcn_s_barrier();
    __builtin_amdgcn_s_setprio(1);
    #pragma unroll
    for (int kk = 0; kk < 2; ++kk)
      #pragma unroll
      for (int mi = 0; mi < 4; ++mi)
        #pragma unroll
        for (int ni = 0; ni < 2; ++ni)
          acc[mi + 4][ni + 2] = __builtin_amdgcn_mfma_f32_16x16x32_bf16(
              af1[kk][mi], bf23[kk][ni], acc[mi + 4][ni + 2], 0, 0, 0);
    __builtin_amdgcn_s_setprio(0);
    __builtin_amdgcn_s_barrier();
  }

  const int rB = mBase + wr * 128, cB = nBase + wc * 64;
  #pragma unroll
  for (int mi = 0; mi < 8; ++mi) {
    #pragma unroll
    for (int ni = 0; ni < 4; ++ni) {
      #pragma unroll
      for (int j2 = 0; j2 < 4; ++j2) {
        int r = rB + mi * 16 + lr * 4 + j2;
        int c = cB + ni * 16 + lc;
        float v = acc[mi][ni][j2] + bias[c];
        if constexpr (EPI == EPI_STORE) {
          outB[(size_t)r * N + c] = __float2bfloat16(v);
        } else {  // EPI_GELU
          float e = __expf(1.5957691216057308f * v + 0.07135481627260086f * v * v * v);
          float t2 = 1.f - 2.f / (e + 1.f);
          outB[(size_t)r * N + c] = __float2bfloat16(0.5f * v * (1.f + t2));
        }
      }
    }
  }
}

// ------------------------------------------------ window attention (attn1, MFMA)
__global__ __launch_bounds__(512, 1) void attn1_mfma(
    const bf16* __restrict__ qkv, const float* __restrict__ rel,
    bf16* __restrict__ o) {
  __shared__ bf16 Ks[256 * 64];
  __shared__ bf16 Vt[64 * 256];
  __shared__ ushort Pl[8][32 * 40];
  __shared__ float bias_s[964];

  const int tid = threadIdx.x;
  const int w = tid >> 6, lane = tid & 63;
  const int p4 = lane >> 4, c = lane & 15;
  const int bh = blockIdx.x, b = bh >> 4, h = bh & 15;
  const bf16* basep = qkv + (size_t)b * 256 * 3072 + h * 64;

  #pragma unroll
  for (int it = 0; it < 4; ++it) {
    int t16 = it * 512 + tid;
    int row = t16 >> 3;
    int sc = ((t16 & 7) ^ (row & 7)) << 3;
    gload_lds16(basep + (size_t)row * 3072 + 1024 + sc, (char*)Ks + t16 * 16);
  }
  #pragma unroll
  for (int it = 0; it < 4; ++it) {
    int i = it * 512 + tid;
    int key = i >> 3, d0 = (i & 7) * 8;
    int4 u = *reinterpret_cast<const int4*>(basep + (size_t)key * 3072 + 2048 + d0);
    const ushort* us = reinterpret_cast<const ushort*>(&u);
    #pragma unroll
    for (int j = 0; j < 8; ++j) {
      int dh = d0 + j;
      int byte = dh * 512 + ((key * 2) ^ ((dh & 7) << 4));
      *reinterpret_cast<ushort*>((char*)Vt + byte) = us[j];
    }
  }
  for (int i = tid; i < 964; i += 512) bias_s[i] = rel[i * 16 + h];

  bf16x8 qf[2][2];
  #pragma unroll
  for (int mi = 0; mi < 2; ++mi)
    #pragma unroll
    for (int s = 0; s < 2; ++s) {
      int q = w * 32 + mi * 16 + c;
      int dh = s * 32 + p4 * 8;
      int4 u = *reinterpret_cast<const int4*>(basep + (size_t)q * 3072 + dh);
      uint32_t a[4] = {(uint32_t)u.x, (uint32_t)u.y, (uint32_t)u.z, (uint32_t)u.w};
      bf16x8 r;
      #pragma unroll
      for (int t = 0; t < 4; ++t) {
        float lo = __uint_as_float(a[t] << 16) * 0.125f;
        float hi = __uint_as_float(a[t] & 0xffff0000u) * 0.125f;
        r[2 * t]     = (short)(__float_as_uint(lo) >> 16);
        r[2 * t + 1] = (short)(__float_as_uint(hi) >> 16);
      }
      qf[mi][s] = r;
    }
  __syncthreads();

  float m_run[2][4], l_run[2][4];
  f32x4 oacc[2][4];
  #pragma unroll
  for (int mi = 0; mi < 2; ++mi)
    #pragma unroll
    for (int j = 0; j < 4; ++j) {
      m_run[mi][j] = -1e30f; l_run[mi][j] = 0.f;
      oacc[mi][j] = f32x4{0.f, 0.f, 0.f, 0.f};
    }

  ushort* Pw = &Pl[w][0];
  const int colterm = p4 * 4 - c + 15;

  for (int kt = 0; kt < 8; ++kt) {
    f32x4 sacc[2][2];
    #pragma unroll
    for (int mi = 0; mi < 2; ++mi)
      #pragma unroll
      for (int nf = 0; nf < 2; ++nf) {
        int bi = ((w * 2 + mi) - (kt * 2 + nf) + 15) * 31 + colterm;
        #pragma unroll
        for (int j = 0; j < 4; ++j) sacc[mi][nf][j] = bias_s[bi + j];
      }
    #pragma unroll
    for (int nf = 0; nf < 2; ++nf) {
      int key = kt * 32 + nf * 16 + c;
      #pragma unroll
      for (int s = 0; s < 2; ++s) {
        int byte = key * 128 + (((s * 4 + p4) ^ (key & 7)) << 4);
        bf16x8 kb = *reinterpret_cast<const bf16x8*>((const char*)Ks + byte);
        #pragma unroll
        for (int mi = 0; mi < 2; ++mi)
          sacc[mi][nf] = __builtin_amdgcn_mfma_f32_16x16x32_bf16(
              qf[mi][s], kb, sacc[mi][nf], 0, 0, 0);
      }
    }
    float sf[2][4];
    #pragma unroll
    for (int mi = 0; mi < 2; ++mi)
      #pragma unroll
      for (int j = 0; j < 4; ++j) {
        float cm = fmaxf(sacc[mi][0][j], sacc[mi][1][j]);
        cm = fmaxf(cm, __shfl_xor(cm, 1));
        cm = fmaxf(cm, __shfl_xor(cm, 2));
        cm = fmaxf(cm, __shfl_xor(cm, 4));
        cm = fmaxf(cm, __shfl_xor(cm, 8));
        float nm = fmaxf(m_run[mi][j], cm);
        sf[mi][j] = __expf(m_run[mi][j] - nm);
        m_run[mi][j] = nm;
        l_run[mi][j] *= sf[mi][j];
      }
    #pragma unroll
    for (int mi = 0; mi < 2; ++mi)
      #pragma unroll
      for (int nf = 0; nf < 4; ++nf)
        #pragma unroll
        for (int j = 0; j < 4; ++j) oacc[mi][nf][j] *= sf[mi][j];
    #pragma unroll
    for (int mi = 0; mi < 2; ++mi) {
      #pragma unroll
      for (int nf = 0; nf < 2; ++nf)
        #pragma unroll
        for (int j = 0; j < 4; ++j)
          sacc[mi][nf][j] = __expf(sacc[mi][nf][j] - m_run[mi][j]);
      #pragma unroll
      for (int j = 0; j < 4; ++j) {
        float lp = sacc[mi][0][j] + sacc[mi][1][j];
        lp += __shfl_xor(lp, 1);
        lp += __shfl_xor(lp, 2);
        lp += __shfl_xor(lp, 4);
        lp += __shfl_xor(lp, 8);
        l_run[mi][j] += lp;
      }
      #pragma unroll
      for (int nf = 0; nf < 2; ++nf)
        #pragma unroll
        for (int j = 0; j < 4; ++j)
          Pw[(mi * 16 + p4 * 4 + j) * 40 + nf * 16 + c] =
              f2bf_bits(sacc[mi][nf][j]);
    }
    bf16x8 pa[2], vb[4];
    #pragma unroll
    for (int mi = 0; mi < 2; ++mi)
      pa[mi] = *reinterpret_cast<const bf16x8*>(
          (const char*)Pw + (mi * 16 + c) * 80 + p4 * 16);
    #pragma unroll
    for (int nf = 0; nf < 4; ++nf) {
      int dh = nf * 16 + c;
      int byte = dh * 512 + (((kt * 4 + p4) ^ (dh & 7)) << 4);
      vb[nf] = *reinterpret_cast<const bf16x8*>((const char*)Vt + byte);
    }
    #pragma unroll
    for (int mi = 0; mi < 2; ++mi)
      #pragma unroll
      for (int nf = 0; nf < 4; ++nf)
        oacc[mi][nf] = __builtin_amdgcn_mfma_f32_16x16x32_bf16(
            pa[mi], vb[nf], oacc[mi][nf], 0, 0, 0);
  }

  #pragma unroll
  for (int mi = 0; mi < 2; ++mi) {
    float inv[4];
    #pragma unroll
    for (int j = 0; j < 4; ++j) inv[j] = 1.f / l_run[mi][j];
    #pragma unroll
    for (int nf = 0; nf < 4; ++nf)
      #pragma unroll
      for (int j = 0; j < 4; ++j) {
        int q = w * 32 + mi * 16 + p4 * 4 + j;
        int dh = nf * 16 + c;
        o[((size_t)b * 256 + q) * 1024 + h * 64 + dh] =
            __float2bfloat16(oacc[mi][nf][j] * inv[j]);
      }
  }
}

// ------------------------------------------------ cross attention (attn2, MFMA)
__global__ __launch_bounds__(512, 1) void attn2_mfma(
    const bf16* __restrict__ q2, const bf16* __restrict__ kv,
    bf16* __restrict__ o2) {
  __shared__ bf16 Ks[80 * 64];
  __shared__ bf16 Vt[64 * 128];
  __shared__ ushort Pl[8][32 * 104];

  const int tid = threadIdx.x;
  const int w = tid >> 6, lane = tid & 63;
  const int p4 = lane >> 4, c = lane & 15;
  const int bh = blockIdx.x, b = bh >> 4, h = bh & 15;
  const size_t kvrow0 = (size_t)b * 77;

  {
    int t16 = tid;
    int key = t16 >> 3;
    int sc = ((t16 & 7) ^ (key & 7)) << 3;
    gload_lds16(kv + (kvrow0 + key) * 2048 + h * 64 + sc, (char*)Ks + t16 * 16);
    if (tid < 128) {
      int u16 = 512 + tid; key = u16 >> 3;
      sc = ((u16 & 7) ^ (key & 7)) << 3;
      gload_lds16(kv + (kvrow0 + key) * 2048 + h * 64 + sc, (char*)Ks + u16 * 16);
    }
  }
  for (int i = tid; i < 80 * 8; i += 512) {
    int key = i >> 3, d0 = (i & 7) * 8;
    int4 u = *reinterpret_cast<const int4*>(
        kv + (kvrow0 + key) * 2048 + 1024 + h * 64 + d0);
    const ushort* us = reinterpret_cast<const ushort*>(&u);
    #pragma unroll
    for (int j = 0; j < 8; ++j) {
      int dh = d0 + j;
      int byte = dh * 256 + ((key * 2) ^ ((dh & 7) << 4));
      *reinterpret_cast<ushort*>((char*)Vt + byte) = us[j];
    }
  }
  {
    int row = lane >> 1, colb = 160 + (lane & 1) * 16;
    *reinterpret_cast<int4*>((char*)&Pl[w][0] + row * 208 + colb) =
        int4{0, 0, 0, 0};
  }
  bf16x8 qf[2][2];
  #pragma unroll
  for (int mi = 0; mi < 2; ++mi)
    #pragma unroll
    for (int s = 0; s < 2; ++s) {
      int q = w * 32 + mi * 16 + c;
      int dh = s * 32 + p4 * 8;
      int4 u = *reinterpret_cast<const int4*>(
          q2 + ((size_t)b * 256 + q) * 1024 + h * 64 + dh);
      uint32_t a[4] = {(uint32_t)u.x, (uint32_t)u.y, (uint32_t)u.z, (uint32_t)u.w};
      bf16x8 r;
      #pragma unroll
      for (int t = 0; t < 4; ++t) {
        float lo = __uint_as_float(a[t] << 16) * 0.125f;
        float hi = __uint_as_float(a[t] & 0xffff0000u) * 0.125f;
        r[2 * t]     = (short)(__float_as_uint(lo) >> 16);
        r[2 * t + 1] = (short)(__float_as_uint(hi) >> 16);
      }
      qf[mi][s] = r;
    }
  __syncthreads();

  f32x4 sacc[2][5];
  #pragma unroll
  for (int mi = 0; mi < 2; ++mi)
    #pragma unroll
    for (int nf = 0; nf < 5; ++nf)
      sacc[mi][nf] = f32x4{0.f, 0.f, 0.f, 0.f};
  #pragma unroll
  for (int nf = 0; nf < 5; ++nf) {
    int key = nf * 16 + c;
    #pragma unroll
    for (int s = 0; s < 2; ++s) {
      int byte = key * 128 + (((s * 4 + p4) ^ (key & 7)) << 4);
      bf16x8 kb = *reinterpret_cast<const bf16x8*>((const char*)Ks + byte);
      #pragma unroll
      for (int mi = 0; mi < 2; ++mi)
        sacc[mi][nf] = __builtin_amdgcn_mfma_f32_16x16x32_bf16(
            qf[mi][s], kb, sacc[mi][nf], 0, 0, 0);
    }
  }
  if (c >= 13) {
    #pragma unroll
    for (int mi = 0; mi < 2; ++mi)
      #pragma unroll
      for (int j = 0; j < 4; ++j) sacc[mi][4][j] = -1e30f;
  }
  float lrow[2][4];
  #pragma unroll
  for (int mi = 0; mi < 2; ++mi)
    #pragma unroll
    for (int j = 0; j < 4; ++j) {
      float cm = sacc[mi][0][j];
      #pragma unroll
      for (int nf = 1; nf < 5; ++nf) cm = fmaxf(cm, sacc[mi][nf][j]);
      cm = fmaxf(cm, __shfl_xor(cm, 1));
      cm = fmaxf(cm, __shfl_xor(cm, 2));
      cm = fmaxf(cm, __shfl_xor(cm, 4));
      cm = fmaxf(cm, __shfl_xor(cm, 8));
      float lp = 0.f;
      #pragma unroll
      for (int nf = 0; nf < 5; ++nf) {
        sacc[mi][nf][j] = __expf(sacc[mi][nf][j] - cm);
        lp += sacc[mi][nf][j];
      }
      lp += __shfl_xor(lp, 1);
      lp += __shfl_xor(lp, 2);
      lp += __shfl_xor(lp, 4);
      lp += __shfl_xor(lp, 8);
      lrow[mi][j] = lp;
    }
  ushort* Pw = &Pl[w][0];
  #pragma unroll
  for (int mi = 0; mi < 2; ++mi)
    #pragma unroll
    for (int nf = 0; nf < 5; ++nf)
      #pragma unroll
      for (int j = 0; j < 4; ++j)
        Pw[(mi * 16 + p4 * 4 + j) * 104 + nf * 16 + c] =
            f2bf_bits(sacc[mi][nf][j]);
  f32x4 oacc[2][4];
  #pragma unroll
  for (int mi = 0; mi < 2; ++mi)
    #pragma unroll
    for (int nf = 0; nf < 4; ++nf) oacc[mi][nf] = f32x4{0.f, 0.f, 0.f, 0.f};
  #pragma unroll
  for (int kk = 0; kk < 3; ++kk) {
    bf16x8 pa[2], vb[4];
    #pragma unroll
    for (int mi = 0; mi < 2; ++mi)
      pa[mi] = *reinterpret_cast<const bf16x8*>(
          (const char*)Pw + (mi * 16 + c) * 208 + kk * 64 + p4 * 16);
    #pragma unroll
    for (int nf = 0; nf < 4; ++nf) {
      int dh = nf * 16 + c;
      int byte = dh * 256 + (((kk * 4 + p4) ^ (dh & 7)) << 4);
      vb[nf] = *reinterpret_cast<const bf16x8*>((const char*)Vt + byte);
    }
    #pragma unroll
    for (int mi = 0; mi < 2; ++mi)
      #pragma unroll
      for (int nf = 0; nf < 4; ++nf)
        oacc[mi][nf] = __builtin_amdgcn_mfma_f32_16x16x32_bf16(
            pa[mi], vb[nf], oacc[mi][nf], 0, 0, 0);
  }
  #pragma unroll
  for (int mi = 0; mi < 2; ++mi) {
    float inv[4];
    #pragma unroll
    for (int j = 0; j < 4; ++j) inv[j] = 1.f / lrow[mi][j];
    #pragma unroll
    for (int nf = 0; nf < 4; ++nf)
      #pragma unroll
      for (int j = 0; j < 4; ++j) {
        int q = w * 32 + mi * 16 + p4 * 4 + j;
        int dh = nf * 16 + c;
        o2[((size_t)b * 256 + q) * 1024 + h * 64 + dh] =
            __float2bfloat16(oacc[mi][nf][j] * inv[j]);
      }
  }
}

// ---------------------------------------------------------------- launcher

extern "C" void kernel_launch(void* const* d_in, const int* in_sizes, int n_in,
                              void* d_out, int out_size, void* d_ws, size_t ws_size,
                              hipStream_t stream) {
  (void)in_sizes; (void)n_in; (void)out_size; (void)ws_size;
  const float* x      = (const float*)d_in[0];
  const float* noise  = (const float*)d_in[1];
  const float* y      = (const float*)d_in[2];
  const float* W_qkv  = (const float*)d_in[3];
  const float* b_qkv  = (const float*)d_in[4];
  const float* W_proj = (const float*)d_in[5];
  const float* b_proj = (const float*)d_in[6];
  const float* rel    = (const float*)d_in[7];
  const float* W_ada  = (const float*)d_in[8];
  const float* b_ada  = (const float*)d_in[9];
  const float* W_fc1  = (const float*)d_in[10];
  const float* b_fc1  = (const float*)d_in[11];
  const float* W_fc2  = (const float*)d_in[12];
  const float* b_fc2  = (const float*)d_in[13];
  const float* W_q    = (const float*)d_in[14];
  const float* W_kv   = (const float*)d_in[15];

  char* ws = (char*)d_ws;
  size_t off = 0;
  auto alloc = [&](size_t bytes) {
    char* p = ws + off;
    off = (off + bytes + 255) & ~(size_t)255;
    return p;
  };
  float* ada   = (float*)alloc(32u * 6144 * 4);
  float* xcur  = (float*)alloc(8192u * 1024 * 4);
  bf16* WqkvT  = (bf16*)alloc(3072u * 1024 * 2);
  bf16* WprojT = (bf16*)alloc(1024u * 1024 * 2);
  bf16* WqT    = (bf16*)alloc(1024u * 1024 * 2);
  bf16* WkvT   = (bf16*)alloc(2048u * 1024 * 2);
  bf16* Wfc1T  = (bf16*)alloc(4096u * 1024 * 2);
  bf16* Wfc2T  = (bf16*)alloc(1024u * 4096 * 2);
  bf16* WadaT  = (bf16*)alloc(6144u * 1024 * 2);
  bf16* Apad   = (bf16*)alloc(128u * 1024 * 2);
  bf16* hbuf   = (bf16*)alloc(8192u * 1024 * 2);
  bf16* big    = (bf16*)alloc(8192u * 4096 * 2);
  bf16* obuf   = (bf16*)alloc(8192u * 1024 * 2);
  bf16* kvbuf  = (bf16*)alloc(2560u * 2048 * 2);
  bf16* ybuf   = (bf16*)alloc(2560u * 1024 * 2);
  float* outF  = (float*)d_out;

  // fused prep: all transposes + y conv + silu in one launch (32256 blocks)
  prep_all<<<32256, 256, 0, stream>>>(
      W_qkv, W_proj, W_q, W_kv, W_fc1, W_fc2, W_ada, y, noise,
      WqkvT, WprojT, WqT, WkvT, Wfc1T, Wfc2T, WadaT, ybuf, Apad);

  // ada = silu(noise) @ W_ada + b_ada (M=32 padded to 128)
  gemm_bf16<EPI_ADAF><<<48, 256, 0, stream>>>(
      Apad, WadaT, 6144, 1024, 48, 8, 1, b_ada, nullptr, 0, nullptr, ada, nullptr);

  // MSA branch
  ln_mod<<<8192, 256, 0, stream>>>(x, ada, 0, 1024, hbuf);
  gemm8q<EPI_STORE><<<384, 512, 0, stream>>>(            // qkv: 12x32 tiles 256^2
      hbuf, WqkvT, 3072, 1024, 12, 4, 2, b_qkv, big);
  attn1_mfma<<<512, 512, 0, stream>>>(big, rel, obuf);
  gemm_bf16<EPI_PROJ><<<512, 256, 0, stream>>>(          // proj: 8x64 tiles 128^2
      obuf, WprojT, 1024, 1024, 8, 1, 8, b_proj, ada, 2048, x, xcur, hbuf);

  // cross-attention branch (head-major q2/kv)
  gemm_bf16<EPI_STORE><<<512, 256, 0, stream>>>(         // q2: 8x64 tiles 128^2
      hbuf, WqT, 1024, 1024, 8, 1, 8, nullptr, nullptr, 0, nullptr, nullptr, obuf);
  gemm_bf16<EPI_STORE><<<320, 256, 0, stream>>>(         // kv: 16x20 tiles 128^2
      ybuf, WkvT, 2048, 1024, 16, 8, 1, nullptr, nullptr, 0, nullptr, nullptr, kvbuf);
  attn2_mfma<<<512, 512, 0, stream>>>(obuf, kvbuf, big);
  // fused: xcur += perm(o2); hbuf = modulate(LN(xcur))
  permute_ln<<<8192, 256, 0, stream>>>(big, xcur, ada, 3072, 4096, hbuf);

  // MLP branch
  gemm8q<EPI_GELU><<<512, 512, 0, stream>>>(             // fc1: 16x32 tiles 256^2
      hbuf, Wfc1T, 4096, 1024, 16, 4, 2, b_fc1, big);
  gemm_bf16<EPI_OUT><<<512, 256, 0, stream>>>(           // fc2: 8x64 tiles 128^2
      big, Wfc2T, 1024, 4096, 8, 1, 8, b_fc2, ada, 5120, xcur, outF, nullptr);
}

// Round 18
// 486.805 us; speedup vs baseline: 1.0813x; 1.0097x over previous
//
#include <hip/hip_runtime.h>
#include <hip/hip_bf16.h>
#include <stdint.h>

typedef __hip_bfloat16 bf16;
using bf16x8 = __attribute__((ext_vector_type(8))) short;   // 8 bf16 (4 VGPRs)
using f32x4  = __attribute__((ext_vector_type(4))) float;   // 4 fp32

// ---------------------------------------------------------------- utilities

__device__ __forceinline__ void gload_lds16(const void* g, void* l) {
  using gchar = __attribute__((address_space(1))) char;
  using lchar = __attribute__((address_space(3))) char;
  gchar* gp = reinterpret_cast<gchar*>(reinterpret_cast<uintptr_t>(g));
  lchar* lp = reinterpret_cast<lchar*>(static_cast<uint32_t>(reinterpret_cast<uintptr_t>(l)));
  __builtin_amdgcn_global_load_lds(gp, lp, 16, 0, 0);
}

__device__ __forceinline__ unsigned short f2bf_bits(float x) {
  uint32_t u = __float_as_uint(x);
  uint32_t r = (u + 0x7fffu + ((u >> 16) & 1u)) >> 16;
  return (unsigned short)r;
}

// ------------------------------------------------ fused prep: 7 transposes +
// y->bf16 (pad 2560) + silu(noise)->bf16 (pad 128) in ONE launch.
__global__ __launch_bounds__(256) void prep_all(
    const float* __restrict__ Wqkv, const float* __restrict__ Wproj,
    const float* __restrict__ Wq, const float* __restrict__ Wkv,
    const float* __restrict__ Wfc1, const float* __restrict__ Wfc2,
    const float* __restrict__ Wada, const float* __restrict__ y,
    const float* __restrict__ noise,
    bf16* __restrict__ WqkvT, bf16* __restrict__ WprojT,
    bf16* __restrict__ WqT, bf16* __restrict__ WkvT,
    bf16* __restrict__ Wfc1T, bf16* __restrict__ Wfc2T,
    bf16* __restrict__ WadaT, bf16* __restrict__ yb, bf16* __restrict__ Apad) {
  __shared__ float t[32][33];
  const int tid = threadIdx.x;
  int bid = blockIdx.x;

  const float* W = nullptr; bf16* Wt = nullptr;
  int K = 0, N = 0, nx = 0, perm = 0;
  if (bid < 3072)        { W = Wqkv;  Wt = WqkvT;  K = 1024; N = 3072; nx = 96;  perm = 0; }
  else if (bid < 4096)   { bid -= 3072;  W = Wproj; Wt = WprojT; K = 1024; N = 1024; nx = 32;  perm = 0; }
  else if (bid < 5120)   { bid -= 4096;  W = Wq;    Wt = WqT;    K = 1024; N = 1024; nx = 32;  perm = 1; }
  else if (bid < 7168)   { bid -= 5120;  W = Wkv;   Wt = WkvT;   K = 1024; N = 2048; nx = 64;  perm = 2; }
  else if (bid < 11264)  { bid -= 7168;  W = Wfc1;  Wt = Wfc1T;  K = 1024; N = 4096; nx = 128; perm = 0; }
  else if (bid < 15360)  { bid -= 11264; W = Wfc2;  Wt = Wfc2T;  K = 4096; N = 1024; nx = 32;  perm = 0; }
  else if (bid < 21504)  { bid -= 15360; W = Wada;  Wt = WadaT;  K = 1024; N = 6144; nx = 192; perm = 0; }
  else if (bid < 31744) {                // conv_y: 10240 blocks
    bid -= 21504;
    int i = bid * 256 + tid;
    float v = (i < 2464 * 1024) ? y[i] : 0.f;
    yb[i] = __float2bfloat16(v);
    return;
  } else {                               // silu_pad: 512 blocks
    bid -= 31744;
    int i = bid * 256 + tid;
    float v = 0.f;
    if (i < 32 * 1024) {
      float xx = noise[i];
      v = xx / (1.f + __expf(-xx));
    }
    Apad[i] = __float2bfloat16(v);
    return;
  }

  const int n0 = (bid % nx) * 32, k0 = (bid / nx) * 32;
  const int tx = tid & 31, ty = tid >> 5;
  #pragma unroll
  for (int i = ty; i < 32; i += 8) t[i][tx] = W[(size_t)(k0 + i) * N + n0 + tx];
  __syncthreads();
  #pragma unroll
  for (int i = ty; i < 32; i += 8) {
    int n = n0 + i;
    int np;
    if (perm == 0) np = n;
    else if (perm == 1) np = (n & 15) * 64 + (n >> 4);
    else { int base = n & 1024, m = n & 1023; np = base + (m & 15) * 64 + (m >> 4); }
    Wt[(size_t)np * K + k0 + tx] = __float2bfloat16(t[tx][i]);
  }
}

// ------------------------------------------------ LN + modulate -> bf16
__global__ __launch_bounds__(256) void ln_mod(
    const float* __restrict__ x, const float* __restrict__ ada,
    int shOff, int scOff, bf16* __restrict__ out) {
  const int row = blockIdx.x, b = row >> 8, tid = threadIdx.x;
  const float* xr = x + (size_t)row * 1024;
  float v[4], s = 0.f, ss = 0.f;
  #pragma unroll
  for (int i = 0; i < 4; ++i) {
    v[i] = xr[tid + i * 256];
    s += v[i]; ss += v[i] * v[i];
  }
  #pragma unroll
  for (int o = 32; o; o >>= 1) { s += __shfl_xor(s, o); ss += __shfl_xor(ss, o); }
  __shared__ float red[8];
  const int w = tid >> 6;
  if ((tid & 63) == 0) { red[w] = s; red[w + 4] = ss; }
  __syncthreads();
  s = red[0] + red[1] + red[2] + red[3];
  ss = red[4] + red[5] + red[6] + red[7];
  float mu = s * (1.f / 1024.f);
  float var = ss * (1.f / 1024.f) - mu * mu;
  float rstd = rsqrtf(var + 1e-6f);
  const float* adab = ada + (size_t)b * 6144;
  #pragma unroll
  for (int i = 0; i < 4; ++i) {
    int c = tid + i * 256;
    float o = (v[i] - mu) * rstd * (1.f + adab[scOff + c]) + adab[shOff + c];
    out[(size_t)row * 1024 + c] = __float2bfloat16(o);
  }
}

// ------------------------------------------------ fused o2-permute-add + LN+mod
__global__ __launch_bounds__(256) void permute_ln(
    const bf16* __restrict__ o2, float* __restrict__ xcur,
    const float* __restrict__ ada, int shOff, int scOff,
    bf16* __restrict__ out) {
  __shared__ float s_lds[1088];
  __shared__ float red[8];
  const int row = blockIdx.x, b = row >> 8, tid = threadIdx.x;
  #pragma unroll
  for (int i = 0; i < 4; ++i) {
    int hm = i * 256 + tid;
    float v = __bfloat162float(o2[(size_t)row * 1024 + hm]);
    s_lds[hm + (hm >> 4)] = v;
  }
  __syncthreads();
  float v[4], s = 0.f, ss = 0.f;
  float4* xp = reinterpret_cast<float4*>(xcur + (size_t)row * 1024 + tid * 4);
  float4 cur = *xp;
  #pragma unroll
  for (int tI = 0; tI < 4; ++tI) {
    int c = tid * 4 + tI;
    int src = (c & 15) * 64 + (c >> 4);
    float xv = (&cur.x)[tI] + s_lds[src + (src >> 4)];
    v[tI] = xv; s += xv; ss += xv * xv;
  }
  float4 nw; nw.x = v[0]; nw.y = v[1]; nw.z = v[2]; nw.w = v[3];
  *xp = nw;
  #pragma unroll
  for (int o = 32; o; o >>= 1) { s += __shfl_xor(s, o); ss += __shfl_xor(ss, o); }
  const int w = tid >> 6;
  if ((tid & 63) == 0) { red[w] = s; red[w + 4] = ss; }
  __syncthreads();
  s = red[0] + red[1] + red[2] + red[3];
  ss = red[4] + red[5] + red[6] + red[7];
  float mu = s * (1.f / 1024.f);
  float var = ss * (1.f / 1024.f) - mu * mu;
  float rstd = rsqrtf(var + 1e-6f);
  const float* adab = ada + (size_t)b * 6144;
  #pragma unroll
  for (int tI = 0; tI < 4; ++tI) {
    int c = tid * 4 + tI;
    float o = (v[tI] - mu) * rstd * (1.f + adab[scOff + c]) + adab[shOff + c];
    out[(size_t)row * 1024 + c] = __float2bfloat16(o);
  }
}

// ------------------------------------------------ generic bf16 MFMA GEMM (128^2)
enum { EPI_STORE = 0, EPI_GELU = 1, EPI_PROJ = 2, EPI_OUT = 3, EPI_ADAF = 4 };

template <int EPI>
__global__ __launch_bounds__(256, 2) void gemm_bf16(
    const bf16* __restrict__ A, const bf16* __restrict__ Bt,
    int N, int K, int gx, int grpG, int xcdP,
    const float* __restrict__ bias, const float* __restrict__ ada, int adaOff,
    const float* __restrict__ resid, float* __restrict__ outF,
    bf16* __restrict__ outB) {
  __shared__ bf16 As[128 * 64];
  __shared__ bf16 Bs[128 * 64];
  const int tid = threadIdx.x;
  const int w = tid >> 6, lane = tid & 63;
  const int wr = w >> 1, wc = w & 1;
  const int lr = lane >> 4, lc = lane & 15;

  const int flat = blockIdx.x;
  const int xcd = flat & 7, j = flat >> 3;
  const int cpg = gx / grpG;
  const int grp = xcd / xcdP, par = xcd % xcdP;
  const int bx = grp * cpg + j % cpg;
  const int by = (j / cpg) * xcdP + par;
  const int mBase = by * 128, nBase = bx * 128;

  f32x4 acc[4][4];
  #pragma unroll
  for (int mi = 0; mi < 4; ++mi)
    #pragma unroll
    for (int ni = 0; ni < 4; ++ni)
      #pragma unroll
      for (int j2 = 0; j2 < 4; ++j2) acc[mi][ni][j2] = 0.f;

  const int nK = K >> 6;
  for (int ks = 0; ks < nK; ++ks) {
    const int k0 = ks << 6;
    #pragma unroll
    for (int i = 0; i < 4; ++i) {
      int t16 = w * 256 + i * 64 + lane;
      int row = t16 >> 3;
      int cL = ((t16 & 7) ^ (row & 7)) << 3;
      gload_lds16(A + (size_t)(mBase + row) * K + k0 + cL, (char*)As + t16 * 16);
      gload_lds16(Bt + (size_t)(nBase + row) * K + k0 + cL, (char*)Bs + t16 * 16);
    }
    __syncthreads();
    #pragma unroll
    for (int kk = 0; kk < 2; ++kk) {
      bf16x8 af[4], bfr[4];
      #pragma unroll
      for (int mi = 0; mi < 4; ++mi) {
        int row = wr * 64 + mi * 16 + lc;
        int byte = row * 128 + ((kk * 64 + lr * 16) ^ ((row & 7) << 4));
        af[mi] = *reinterpret_cast<const bf16x8*>((const char*)As + byte);
      }
      #pragma unroll
      for (int ni = 0; ni < 4; ++ni) {
        int row = wc * 64 + ni * 16 + lc;
        int byte = row * 128 + ((kk * 64 + lr * 16) ^ ((row & 7) << 4));
        bfr[ni] = *reinterpret_cast<const bf16x8*>((const char*)Bs + byte);
      }
      #pragma unroll
      for (int mi = 0; mi < 4; ++mi)
        #pragma unroll
        for (int ni = 0; ni < 4; ++ni)
          acc[mi][ni] = __builtin_amdgcn_mfma_f32_16x16x32_bf16(
              af[mi], bfr[ni], acc[mi][ni], 0, 0, 0);
    }
    __syncthreads();
  }

  const int rB = mBase + wr * 64, cB = nBase + wc * 64;
  #pragma unroll
  for (int mi = 0; mi < 4; ++mi) {
    #pragma unroll
    for (int ni = 0; ni < 4; ++ni) {
      #pragma unroll
      for (int j2 = 0; j2 < 4; ++j2) {
        int r = rB + mi * 16 + lr * 4 + j2;
        int c = cB + ni * 16 + lc;
        float v = acc[mi][ni][j2];
        if (bias) v += bias[c];
        if constexpr (EPI == EPI_STORE) {
          outB[(size_t)r * N + c] = __float2bfloat16(v);
        } else if constexpr (EPI == EPI_GELU) {
          float e = __expf(1.5957691216057308f * v + 0.07135481627260086f * v * v * v);
          float t = 1.f - 2.f / (e + 1.f);
          outB[(size_t)r * N + c] = __float2bfloat16(0.5f * v * (1.f + t));
        } else if constexpr (EPI == EPI_PROJ) {
          int b = r >> 8;
          float g = ada[(size_t)b * 6144 + adaOff + c];
          float o = resid[(size_t)r * 1024 + c] + g * v;
          outF[(size_t)r * 1024 + c] = o;
          outB[(size_t)r * 1024 + c] = __float2bfloat16(o);
        } else if constexpr (EPI == EPI_OUT) {
          int b = r >> 8;
          float g = ada[(size_t)b * 6144 + adaOff + c];
          outF[(size_t)r * 1024 + c] = resid[(size_t)r * 1024 + c] + g * v;
        } else {
          if (r < 32) outF[(size_t)r * N + c] = v;
        }
      }
    }
  }
}

// ------------------------------------------------ 256^2 quadrant 8-phase GEMM
// (verified r9-r12) 512 thr = 8 waves (2M x 4N), per-wave C = 128x64. BK=64.
template <int EPI>
__global__ __launch_bounds__(512, 1) void gemm8q(
    const bf16* __restrict__ A, const bf16* __restrict__ Bt,
    int N, int K, int gx, int grpG, int xcdP,
    const float* __restrict__ bias, bf16* __restrict__ outB) {
  __shared__ bf16 AS[2][2][128 * 64];              // 64 KB [par][half]
  __shared__ bf16 BS[2][2][128 * 64];              // 64 KB
  const int tid = threadIdx.x;
  const int w = tid >> 6, lane = tid & 63;
  const int wr = w >> 2, wc = w & 3;
  const int lr = lane >> 4, lc = lane & 15;

  const int flat = blockIdx.x;
  const int xcd = flat & 7, jj = flat >> 3;
  const int cpg = gx / grpG;
  const int grp = xcd / xcdP, par_ = xcd % xcdP;
  const int bx = grp * cpg + jj % cpg;
  const int by = (jj / cpg) * xcdP + par_;
  const int mBase = by * 256, nBase = bx * 256;
  const int nT = K >> 6;

  f32x4 acc[8][4];
  #pragma unroll
  for (int mi = 0; mi < 8; ++mi)
    #pragma unroll
    for (int ni = 0; ni < 4; ++ni) acc[mi][ni] = f32x4{0.f, 0.f, 0.f, 0.f};

  auto STAGE_A = [&](int th, int h) {
    if (th >= nT) return;
    const int k0 = th << 6;
    char* dst = (char*)&AS[th & 1][h][0];
    #pragma unroll
    for (int i = 0; i < 2; ++i) {
      int ck = i * 512 + tid;
      int rr = ck >> 3, c = ck & 7;
      int grow = mBase + (rr & 63) + ((rr >> 6) << 7) + h * 64;
      gload_lds16(A + (size_t)grow * K + k0 + ((c ^ (rr & 7)) << 3), dst + ck * 16);
    }
  };
  auto STAGE_B = [&](int th, int h) {
    if (th >= nT) return;
    const int k0 = th << 6;
    char* dst = (char*)&BS[th & 1][h][0];
    #pragma unroll
    for (int i = 0; i < 2; ++i) {
      int ck = i * 512 + tid;
      int rr = ck >> 3, c = ck & 7;
      int grow = nBase + ((rr >> 5) << 6) + h * 32 + (rr & 31);
      gload_lds16(Bt + (size_t)grow * K + k0 + ((c ^ (rr & 7)) << 3), dst + ck * 16);
    }
  };

  STAGE_A(0, 0); STAGE_A(0, 1); STAGE_B(0, 0); STAGE_B(0, 1);
  STAGE_A(1, 0); STAGE_A(1, 1);

  for (int t = 0; t < nT; ++t) {
    if (t == nT - 1) { asm volatile("s_waitcnt vmcnt(0)" ::: "memory"); }
    else             { asm volatile("s_waitcnt vmcnt(4)" ::: "memory"); }
    __builtin_amdgcn_s_barrier();

    const int p = t & 1;
    const char* A0 = (const char*)&AS[p][0][0];
    const char* A1 = (const char*)&AS[p][1][0];
    const char* B0 = (const char*)&BS[p][0][0];
    const char* B1 = (const char*)&BS[p][1][0];

    bf16x8 af0[2][4], af1[2][4], bf01[2][2], bf23[2][2];

    // ---- P0
    #pragma unroll
    for (int kk = 0; kk < 2; ++kk) {
      #pragma unroll
      for (int mi = 0; mi < 4; ++mi) {
        int rr = wr * 64 + mi * 16 + lc;
        af0[kk][mi] = *reinterpret_cast<const bf16x8*>(
            A0 + rr * 128 + ((kk * 64 + lr * 16) ^ ((rr & 7) << 4)));
      }
      #pragma unroll
      for (int ni = 0; ni < 2; ++ni) {
        int rr = wc * 32 + ni * 16 + lc;
        bf01[kk][ni] = *reinterpret_cast<const bf16x8*>(
            B0 + rr * 128 + ((kk * 64 + lr * 16) ^ ((rr & 7) << 4)));
      }
    }
    STAGE_B(t + 1, 0);
    __builtin_amdgcn_s_barrier();
    asm volatile("s_waitcnt lgkmcnt(0)" ::: "memory");
    __builtin_amdgcn_sched_barrier(0);
    __builtin_amdgcn_s_setprio(1);
    #pragma unroll
    for (int kk = 0; kk < 2; ++kk)
      #pragma unroll
      for (int mi = 0; mi < 4; ++mi)
        #pragma unroll
        for (int ni = 0; ni < 2; ++ni)
          acc[mi][ni] = __builtin_amdgcn_mfma_f32_16x16x32_bf16(
              af0[kk][mi], bf01[kk][ni], acc[mi][ni], 0, 0, 0);
    __builtin_amdgcn_s_setprio(0);
    __builtin_amdgcn_s_barrier();

    // ---- P1
    #pragma unroll
    for (int kk = 0; kk < 2; ++kk)
      #pragma unroll
      for (int ni = 0; ni < 2; ++ni) {
        int rr = wc * 32 + ni * 16 + lc;
        bf23[kk][ni] = *reinterpret_cast<const bf16x8*>(
            B1 + rr * 128 + ((kk * 64 + lr * 16) ^ ((rr & 7) << 4)));
      }
    STAGE_B(t + 1, 1);
    __builtin_amdgcn_s_barrier();
    asm volatile("s_waitcnt lgkmcnt(0)" ::: "memory");
    __builtin_amdgcn_sched_barrier(0);
    __builtin_amdgcn_s_setprio(1);
    #pragma unroll
    for (int kk = 0; kk < 2; ++kk)
      #pragma unroll
      for (int mi = 0; mi < 4; ++mi)
        #pragma unroll
        for (int ni = 0; ni < 2; ++ni)
          acc[mi][ni + 2] = __builtin_amdgcn_mfma_f32_16x16x32_bf16(
              af0[kk][mi], bf23[kk][ni], acc[mi][ni + 2], 0, 0, 0);
    __builtin_amdgcn_s_setprio(0);
    __builtin_amdgcn_s_barrier();

    // ---- P2
    #pragma unroll
    for (int kk = 0; kk < 2; ++kk)
      #pragma unroll
      for (int mi = 0; mi < 4; ++mi) {
        int rr = wr * 64 + mi * 16 + lc;
        af1[kk][mi] = *reinterpret_cast<const bf16x8*>(
            A1 + rr * 128 + ((kk * 64 + lr * 16) ^ ((rr & 7) << 4)));
      }
    STAGE_A(t + 2, 0);
    __builtin_amdgcn_s_barrier();
    asm volatile("s_waitcnt lgkmcnt(0)" ::: "memory");
    __builtin_amdgcn_sched_barrier(0);
    __builtin_amdgcn_s_setprio(1);
    #pragma unroll
    for (int kk = 0; kk < 2; ++kk)
      #pragma unroll
      for (int mi = 0; mi < 4; ++mi)
        #pragma unroll
        for (int ni = 0; ni < 2; ++ni)
          acc[mi + 4][ni] = __builtin_amdgcn_mfma_f32_16x16x32_bf16(
              af1[kk][mi], bf01[kk][ni], acc[mi + 4][ni], 0, 0, 0);
    __builtin_amdgcn_s_setprio(0);
    __builtin_amdgcn_s_barrier();

    // ---- P3
    STAGE_A(t + 2, 1);
    __builtin_amdgcn_s_barrier();
    __builtin_amdgcn_s_setprio(1);
    #pragma unroll
    for (int kk = 0; kk < 2; ++kk)
      #pragma unroll
      for (int mi = 0; mi < 4; ++mi)
        #pragma unroll
        for (int ni = 0; ni < 2; ++ni)
          acc[mi + 4][ni + 2] = __builtin_amdgcn_mfma_f32_16x16x32_bf16(
              af1[kk][mi], bf23[kk][ni], acc[mi + 4][ni + 2], 0, 0, 0);
    __builtin_amdgcn_s_setprio(0);
    __builtin_amdgcn_s_barrier();
  }

  const int rB = mBase + wr * 128, cB = nBase + wc * 64;
  #pragma unroll
  for (int mi = 0; mi < 8; ++mi) {
    #pragma unroll
    for (int ni = 0; ni < 4; ++ni) {
      #pragma unroll
      for (int j2 = 0; j2 < 4; ++j2) {
        int r = rB + mi * 16 + lr * 4 + j2;
        int c = cB + ni * 16 + lc;
        float v = acc[mi][ni][j2] + bias[c];
        if constexpr (EPI == EPI_STORE) {
          outB[(size_t)r * N + c] = __float2bfloat16(v);
        } else {  // EPI_GELU
          float e = __expf(1.5957691216057308f * v + 0.07135481627260086f * v * v * v);
          float t2 = 1.f - 2.f / (e + 1.f);
          outB[(size_t)r * N + c] = __float2bfloat16(0.5f * v * (1.f + t2));
        }
      }
    }
  }
}

// ------------------------------------------------ window attention (attn1, MFMA)
// block = (b,h), 8 waves x 32 q-rows; flash over 8 key-tiles of 32.
// qkv layout: [b][n][3][h][dh], row stride 3072.
__global__ __launch_bounds__(512, 1) void attn1_mfma(
    const bf16* __restrict__ qkv, const float* __restrict__ rel,
    bf16* __restrict__ o) {
  __shared__ bf16 Ks[256 * 64];          // rows XOR-swizzled in 16B chunks
  __shared__ bf16 Vt[64 * 256];          // V transposed [dh][key], XOR-swizzled
  __shared__ ushort Pl[8][32 * 40];      // per-wave P (bf16 bits), stride 40
  __shared__ float bias_s[964];

  const int tid = threadIdx.x;
  const int w = tid >> 6, lane = tid & 63;
  const int p4 = lane >> 4, c = lane & 15;
  const int bh = blockIdx.x, b = bh >> 4, h = bh & 15;
  const bf16* basep = qkv + (size_t)b * 256 * 3072 + h * 64;

  #pragma unroll
  for (int it = 0; it < 4; ++it) {
    int t16 = it * 512 + tid;                       // 0..2047
    int row = t16 >> 3;
    int sc = ((t16 & 7) ^ (row & 7)) << 3;
    gload_lds16(basep + (size_t)row * 3072 + 1024 + sc, (char*)Ks + t16 * 16);
  }
  #pragma unroll
  for (int it = 0; it < 4; ++it) {
    int i = it * 512 + tid;                         // chunk id 0..2047
    int key = i >> 3, d0 = (i & 7) * 8;
    int4 u = *reinterpret_cast<const int4*>(basep + (size_t)key * 3072 + 2048 + d0);
    const ushort* us = reinterpret_cast<const ushort*>(&u);
    #pragma unroll
    for (int j = 0; j < 8; ++j) {
      int dh = d0 + j;
      int byte = dh * 512 + ((key * 2) ^ ((dh & 7) << 4));
      *reinterpret_cast<ushort*>((char*)Vt + byte) = us[j];
    }
  }
  for (int i = tid; i < 964; i += 512) bias_s[i] = rel[i * 16 + h];

  bf16x8 qf[2][2];
  #pragma unroll
  for (int mi = 0; mi < 2; ++mi)
    #pragma unroll
    for (int s = 0; s < 2; ++s) {
      int q = w * 32 + mi * 16 + c;
      int dh = s * 32 + p4 * 8;
      int4 u = *reinterpret_cast<const int4*>(basep + (size_t)q * 3072 + dh);
      uint32_t a[4] = {(uint32_t)u.x, (uint32_t)u.y, (uint32_t)u.z, (uint32_t)u.w};
      bf16x8 r;
      #pragma unroll
      for (int t = 0; t < 4; ++t) {
        float lo = __uint_as_float(a[t] << 16) * 0.125f;
        float hi = __uint_as_float(a[t] & 0xffff0000u) * 0.125f;
        r[2 * t]     = (short)(__float_as_uint(lo) >> 16);   // exact
        r[2 * t + 1] = (short)(__float_as_uint(hi) >> 16);
      }
      qf[mi][s] = r;
    }
  __syncthreads();

  float m_run[2][4], l_run[2][4];
  f32x4 oacc[2][4];
  #pragma unroll
  for (int mi = 0; mi < 2; ++mi)
    #pragma unroll
    for (int j = 0; j < 4; ++j) {
      m_run[mi][j] = -1e30f; l_run[mi][j] = 0.f;
      oacc[mi][j] = f32x4{0.f, 0.f, 0.f, 0.f};
    }

  ushort* Pw = &Pl[w][0];
  const int colterm = p4 * 4 - c + 15;

  for (int kt = 0; kt < 8; ++kt) {
    f32x4 sacc[2][2];
    #pragma unroll
    for (int mi = 0; mi < 2; ++mi)
      #pragma unroll
      for (int nf = 0; nf < 2; ++nf) {
        int bi = ((w * 2 + mi) - (kt * 2 + nf) + 15) * 31 + colterm;
        #pragma unroll
        for (int j = 0; j < 4; ++j) sacc[mi][nf][j] = bias_s[bi + j];
      }
    #pragma unroll
    for (int nf = 0; nf < 2; ++nf) {
      int key = kt * 32 + nf * 16 + c;
      #pragma unroll
      for (int s = 0; s < 2; ++s) {
        int byte = key * 128 + (((s * 4 + p4) ^ (key & 7)) << 4);
        bf16x8 kb = *reinterpret_cast<const bf16x8*>((const char*)Ks + byte);
        #pragma unroll
        for (int mi = 0; mi < 2; ++mi)
          sacc[mi][nf] = __builtin_amdgcn_mfma_f32_16x16x32_bf16(
              qf[mi][s], kb, sacc[mi][nf], 0, 0, 0);
      }
    }
    float sf[2][4];
    #pragma unroll
    for (int mi = 0; mi < 2; ++mi)
      #pragma unroll
      for (int j = 0; j < 4; ++j) {
        float cm = fmaxf(sacc[mi][0][j], sacc[mi][1][j]);
        cm = fmaxf(cm, __shfl_xor(cm, 1));
        cm = fmaxf(cm, __shfl_xor(cm, 2));
        cm = fmaxf(cm, __shfl_xor(cm, 4));
        cm = fmaxf(cm, __shfl_xor(cm, 8));
        float nm = fmaxf(m_run[mi][j], cm);
        sf[mi][j] = __expf(m_run[mi][j] - nm);
        m_run[mi][j] = nm;
        l_run[mi][j] *= sf[mi][j];
      }
    #pragma unroll
    for (int mi = 0; mi < 2; ++mi)
      #pragma unroll
      for (int nf = 0; nf < 4; ++nf)
        #pragma unroll
        for (int j = 0; j < 4; ++j) oacc[mi][nf][j] *= sf[mi][j];
    #pragma unroll
    for (int mi = 0; mi < 2; ++mi) {
      #pragma unroll
      for (int nf = 0; nf < 2; ++nf)
        #pragma unroll
        for (int j = 0; j < 4; ++j)
          sacc[mi][nf][j] = __expf(sacc[mi][nf][j] - m_run[mi][j]);
      #pragma unroll
      for (int j = 0; j < 4; ++j) {
        float lp = sacc[mi][0][j] + sacc[mi][1][j];
        lp += __shfl_xor(lp, 1);
        lp += __shfl_xor(lp, 2);
        lp += __shfl_xor(lp, 4);
        lp += __shfl_xor(lp, 8);
        l_run[mi][j] += lp;
      }
      #pragma unroll
      for (int nf = 0; nf < 2; ++nf)
        #pragma unroll
        for (int j = 0; j < 4; ++j)
          Pw[(mi * 16 + p4 * 4 + j) * 40 + nf * 16 + c] =
              f2bf_bits(sacc[mi][nf][j]);
    }
    bf16x8 pa[2], vb[4];
    #pragma unroll
    for (int mi = 0; mi < 2; ++mi)
      pa[mi] = *reinterpret_cast<const bf16x8*>(
          (const char*)Pw + (mi * 16 + c) * 80 + p4 * 16);
    #pragma unroll
    for (int nf = 0; nf < 4; ++nf) {
      int dh = nf * 16 + c;
      int byte = dh * 512 + (((kt * 4 + p4) ^ (dh & 7)) << 4);
      vb[nf] = *reinterpret_cast<const bf16x8*>((const char*)Vt + byte);
    }
    #pragma unroll
    for (int mi = 0; mi < 2; ++mi)
      #pragma unroll
      for (int nf = 0; nf < 4; ++nf)
        oacc[mi][nf] = __builtin_amdgcn_mfma_f32_16x16x32_bf16(
            pa[mi], vb[nf], oacc[mi][nf], 0, 0, 0);
  }

  #pragma unroll
  for (int mi = 0; mi < 2; ++mi) {
    float inv[4];
    #pragma unroll
    for (int j = 0; j < 4; ++j) inv[j] = 1.f / l_run[mi][j];
    #pragma unroll
    for (int nf = 0; nf < 4; ++nf)
      #pragma unroll
      for (int j = 0; j < 4; ++j) {
        int q = w * 32 + mi * 16 + p4 * 4 + j;
        int dh = nf * 16 + c;
        o[((size_t)b * 256 + q) * 1024 + h * 64 + dh] =
            __float2bfloat16(oacc[mi][nf][j] * inv[j]);
      }
  }
}

// ------------------------------------------------ cross attention (attn2, MFMA)
// Inputs head-major: q2[b][n][h*64+d], kv[b][m][h*64+d] (+1024 for v).
__global__ __launch_bounds__(512, 1) void attn2_mfma(
    const bf16* __restrict__ q2, const bf16* __restrict__ kv,
    bf16* __restrict__ o2) {
  __shared__ bf16 Ks[80 * 64];            // swizzled rows (128B each), 10 KB
  __shared__ bf16 Vt[64 * 128];           // [dh][key], 256B rows, 16 KB
  __shared__ ushort Pl[8][32 * 104];      // P bf16, stride 104 elems, 52 KB

  const int tid = threadIdx.x;
  const int w = tid >> 6, lane = tid & 63;
  const int p4 = lane >> 4, c = lane & 15;
  const int bh = blockIdx.x, b = bh >> 4, h = bh & 15;
  const size_t kvrow0 = (size_t)b * 77;

  {
    int t16 = tid;                                  // 0..511
    int key = t16 >> 3;
    int sc = ((t16 & 7) ^ (key & 7)) << 3;
    gload_lds16(kv + (kvrow0 + key) * 2048 + h * 64 + sc, (char*)Ks + t16 * 16);
    if (tid < 128) {
      int u16 = 512 + tid; key = u16 >> 3;
      sc = ((u16 & 7) ^ (key & 7)) << 3;
      gload_lds16(kv + (kvrow0 + key) * 2048 + h * 64 + sc, (char*)Ks + u16 * 16);
    }
  }
  for (int i = tid; i < 80 * 8; i += 512) {
    int key = i >> 3, d0 = (i & 7) * 8;
    int4 u = *reinterpret_cast<const int4*>(
        kv + (kvrow0 + key) * 2048 + 1024 + h * 64 + d0);
    const ushort* us = reinterpret_cast<const ushort*>(&u);
    #pragma unroll
    for (int j = 0; j < 8; ++j) {
      int dh = d0 + j;
      int byte = dh * 256 + ((key * 2) ^ ((dh & 7) << 4));
      *reinterpret_cast<ushort*>((char*)Vt + byte) = us[j];
    }
  }
  {
    int row = lane >> 1, colb = 160 + (lane & 1) * 16;
    *reinterpret_cast<int4*>((char*)&Pl[w][0] + row * 208 + colb) =
        int4{0, 0, 0, 0};
  }
  bf16x8 qf[2][2];
  #pragma unroll
  for (int mi = 0; mi < 2; ++mi)
    #pragma unroll
    for (int s = 0; s < 2; ++s) {
      int q = w * 32 + mi * 16 + c;
      int dh = s * 32 + p4 * 8;
      int4 u = *reinterpret_cast<const int4*>(
          q2 + ((size_t)b * 256 + q) * 1024 + h * 64 + dh);
      uint32_t a[4] = {(uint32_t)u.x, (uint32_t)u.y, (uint32_t)u.z, (uint32_t)u.w};
      bf16x8 r;
      #pragma unroll
      for (int t = 0; t < 4; ++t) {
        float lo = __uint_as_float(a[t] << 16) * 0.125f;
        float hi = __uint_as_float(a[t] & 0xffff0000u) * 0.125f;
        r[2 * t]     = (short)(__float_as_uint(lo) >> 16);
        r[2 * t + 1] = (short)(__float_as_uint(hi) >> 16);
      }
      qf[mi][s] = r;
    }
  __syncthreads();

  f32x4 sacc[2][5];
  #pragma unroll
  for (int mi = 0; mi < 2; ++mi)
    #pragma unroll
    for (int nf = 0; nf < 5; ++nf)
      sacc[mi][nf] = f32x4{0.f, 0.f, 0.f, 0.f};
  #pragma unroll
  for (int nf = 0; nf < 5; ++nf) {
    int key = nf * 16 + c;
    #pragma unroll
    for (int s = 0; s < 2; ++s) {
      int byte = key * 128 + (((s * 4 + p4) ^ (key & 7)) << 4);
      bf16x8 kb = *reinterpret_cast<const bf16x8*>((const char*)Ks + byte);
      #pragma unroll
      for (int mi = 0; mi < 2; ++mi)
        sacc[mi][nf] = __builtin_amdgcn_mfma_f32_16x16x32_bf16(
            qf[mi][s], kb, sacc[mi][nf], 0, 0, 0);
    }
  }
  if (c >= 13) {
    #pragma unroll
    for (int mi = 0; mi < 2; ++mi)
      #pragma unroll
      for (int j = 0; j < 4; ++j) sacc[mi][4][j] = -1e30f;
  }
  float lrow[2][4];
  #pragma unroll
  for (int mi = 0; mi < 2; ++mi)
    #pragma unroll
    for (int j = 0; j < 4; ++j) {
      float cm = sacc[mi][0][j];
      #pragma unroll
      for (int nf = 1; nf < 5; ++nf) cm = fmaxf(cm, sacc[mi][nf][j]);
      cm = fmaxf(cm, __shfl_xor(cm, 1));
      cm = fmaxf(cm, __shfl_xor(cm, 2));
      cm = fmaxf(cm, __shfl_xor(cm, 4));
      cm = fmaxf(cm, __shfl_xor(cm, 8));
      float lp = 0.f;
      #pragma unroll
      for (int nf = 0; nf < 5; ++nf) {
        sacc[mi][nf][j] = __expf(sacc[mi][nf][j] - cm);
        lp += sacc[mi][nf][j];
      }
      lp += __shfl_xor(lp, 1);
      lp += __shfl_xor(lp, 2);
      lp += __shfl_xor(lp, 4);
      lp += __shfl_xor(lp, 8);
      lrow[mi][j] = lp;
    }
  ushort* Pw = &Pl[w][0];
  #pragma unroll
  for (int mi = 0; mi < 2; ++mi)
    #pragma unroll
    for (int nf = 0; nf < 5; ++nf)
      #pragma unroll
      for (int j = 0; j < 4; ++j)
        Pw[(mi * 16 + p4 * 4 + j) * 104 + nf * 16 + c] =
            f2bf_bits(sacc[mi][nf][j]);
  f32x4 oacc[2][4];
  #pragma unroll
  for (int mi = 0; mi < 2; ++mi)
    #pragma unroll
    for (int nf = 0; nf < 4; ++nf) oacc[mi][nf] = f32x4{0.f, 0.f, 0.f, 0.f};
  #pragma unroll
  for (int kk = 0; kk < 3; ++kk) {
    bf16x8 pa[2], vb[4];
    #pragma unroll
    for (int mi = 0; mi < 2; ++mi)
      pa[mi] = *reinterpret_cast<const bf16x8*>(
          (const char*)Pw + (mi * 16 + c) * 208 + kk * 64 + p4 * 16);
    #pragma unroll
    for (int nf = 0; nf < 4; ++nf) {
      int dh = nf * 16 + c;
      int byte = dh * 256 + (((kk * 4 + p4) ^ (dh & 7)) << 4);
      vb[nf] = *reinterpret_cast<const bf16x8*>((const char*)Vt + byte);
    }
    #pragma unroll
    for (int mi = 0; mi < 2; ++mi)
      #pragma unroll
      for (int nf = 0; nf < 4; ++nf)
        oacc[mi][nf] = __builtin_amdgcn_mfma_f32_16x16x32_bf16(
            pa[mi], vb[nf], oacc[mi][nf], 0, 0, 0);
  }
  #pragma unroll
  for (int mi = 0; mi < 2; ++mi) {
    float inv[4];
    #pragma unroll
    for (int j = 0; j < 4; ++j) inv[j] = 1.f / lrow[mi][j];
    #pragma unroll
    for (int nf = 0; nf < 4; ++nf)
      #pragma unroll
      for (int j = 0; j < 4; ++j) {
        int q = w * 32 + mi * 16 + p4 * 4 + j;
        int dh = nf * 16 + c;
        o2[((size_t)b * 256 + q) * 1024 + h * 64 + dh] =
            __float2bfloat16(oacc[mi][nf][j] * inv[j]);
      }
  }
}

// ---------------------------------------------------------------- launcher

extern "C" void kernel_launch(void* const* d_in, const int* in_sizes, int n_in,
                              void* d_out, int out_size, void* d_ws, size_t ws_size,
                              hipStream_t stream) {
  (void)in_sizes; (void)n_in; (void)out_size; (void)ws_size;
  const float* x      = (const float*)d_in[0];
  const float* noise  = (const float*)d_in[1];
  const float* y      = (const float*)d_in[2];
  const float* W_qkv  = (const float*)d_in[3];
  const float* b_qkv  = (const float*)d_in[4];
  const float* W_proj = (const float*)d_in[5];
  const float* b_proj = (const float*)d_in[6];
  const float* rel    = (const float*)d_in[7];
  const float* W_ada  = (const float*)d_in[8];
  const float* b_ada  = (const float*)d_in[9];
  const float* W_fc1  = (const float*)d_in[10];
  const float* b_fc1  = (const float*)d_in[11];
  const float* W_fc2  = (const float*)d_in[12];
  const float* b_fc2  = (const float*)d_in[13];
  const float* W_q    = (const float*)d_in[14];
  const float* W_kv   = (const float*)d_in[15];

  char* ws = (char*)d_ws;
  size_t off = 0;
  auto alloc = [&](size_t bytes) {
    char* p = ws + off;
    off = (off + bytes + 255) & ~(size_t)255;
    return p;
  };
  float* ada   = (float*)alloc(32u * 6144 * 4);
  float* xcur  = (float*)alloc(8192u * 1024 * 4);
  bf16* WqkvT  = (bf16*)alloc(3072u * 1024 * 2);
  bf16* WprojT = (bf16*)alloc(1024u * 1024 * 2);
  bf16* WqT    = (bf16*)alloc(1024u * 1024 * 2);
  bf16* WkvT   = (bf16*)alloc(2048u * 1024 * 2);
  bf16* Wfc1T  = (bf16*)alloc(4096u * 1024 * 2);
  bf16* Wfc2T  = (bf16*)alloc(1024u * 4096 * 2);
  bf16* WadaT  = (bf16*)alloc(6144u * 1024 * 2);
  bf16* Apad   = (bf16*)alloc(128u * 1024 * 2);
  bf16* hbuf   = (bf16*)alloc(8192u * 1024 * 2);
  bf16* big    = (bf16*)alloc(8192u * 4096 * 2);
  bf16* obuf   = (bf16*)alloc(8192u * 1024 * 2);
  bf16* kvbuf  = (bf16*)alloc(2560u * 2048 * 2);
  bf16* ybuf   = (bf16*)alloc(2560u * 1024 * 2);
  float* outF  = (float*)d_out;

  // fused prep: all transposes + y conv + silu in one launch (32256 blocks)
  prep_all<<<32256, 256, 0, stream>>>(
      W_qkv, W_proj, W_q, W_kv, W_fc1, W_fc2, W_ada, y, noise,
      WqkvT, WprojT, WqT, WkvT, Wfc1T, Wfc2T, WadaT, ybuf, Apad);

  // ada = silu(noise) @ W_ada + b_ada (M=32 padded to 128)
  gemm_bf16<EPI_ADAF><<<48, 256, 0, stream>>>(
      Apad, WadaT, 6144, 1024, 48, 8, 1, b_ada, nullptr, 0, nullptr, ada, nullptr);

  // MSA branch
  ln_mod<<<8192, 256, 0, stream>>>(x, ada, 0, 1024, hbuf);
  gemm8q<EPI_STORE><<<384, 512, 0, stream>>>(            // qkv: 12x32 tiles 256^2
      hbuf, WqkvT, 3072, 1024, 12, 4, 2, b_qkv, big);
  attn1_mfma<<<512, 512, 0, stream>>>(big, rel, obuf);
  gemm_bf16<EPI_PROJ><<<512, 256, 0, stream>>>(          // proj: 8x64 tiles 128^2
      obuf, WprojT, 1024, 1024, 8, 1, 8, b_proj, ada, 2048, x, xcur, hbuf);

  // cross-attention branch (head-major q2/kv)
  gemm_bf16<EPI_STORE><<<512, 256, 0, stream>>>(         // q2: 8x64 tiles 128^2
      hbuf, WqT, 1024, 1024, 8, 1, 8, nullptr, nullptr, 0, nullptr, nullptr, obuf);
  gemm_bf16<EPI_STORE><<<320, 256, 0, stream>>>(         // kv: 16x20 tiles 128^2
      ybuf, WkvT, 2048, 1024, 16, 8, 1, nullptr, nullptr, 0, nullptr, nullptr, kvbuf);
  attn2_mfma<<<512, 512, 0, stream>>>(obuf, kvbuf, big);
  // fused: xcur += perm(o2); hbuf = modulate(LN(xcur))
  permute_ln<<<8192, 256, 0, stream>>>(big, xcur, ada, 3072, 4096, hbuf);

  // MLP branch
  gemm8q<EPI_GELU><<<512, 512, 0, stream>>>(             // fc1: 16x32 tiles 256^2
      hbuf, Wfc1T, 4096, 1024, 16, 4, 2, b_fc1, big);
  gemm_bf16<EPI_OUT><<<512, 256, 0, stream>>>(           // fc2: 8x64 tiles 128^2
      big, Wfc2T, 1024, 4096, 8, 1, 8, b_fc2, ada, 5120, xcur, outF, nullptr);
}